// Round 9
// baseline (1956.434 us; speedup 1.0000x reference)
//
#include <hip/hip_runtime.h>
#include <hip/hip_cooperative_groups.h>

namespace cg = cooperative_groups;

#define C_DIM 128
#define H_DIM 256
#define L_NUM 4

typedef __attribute__((ext_vector_type(8))) short bf16x8;
typedef __attribute__((ext_vector_type(4))) float f32x4;

__device__ __forceinline__ unsigned short f2bf(float f){
  unsigned u = __builtin_bit_cast(unsigned, f);
  u = u + 0x7FFFu + ((u >> 16) & 1u);   // round-to-nearest-even
  return (unsigned short)(u >> 16);
}
__device__ __forceinline__ float bf2f(unsigned short b){
  return __builtin_bit_cast(float, ((unsigned)b) << 16);
}

struct Params {
  const float* x; const int* src; const int* dst;
  const float* W1; const float* b1; const float* lnw; const float* lnb;
  const float* W2; const float* b2; const float* tpt;
  const float* gnw; const float* gnb; const float* gna;
  const float* linw; const float* linb;
  float* out;
  int* cnt; int* rp; int* bsum; int* boff; int* csrc;
  float* gncoef; float* lnpart; float* part; float* xc;
  unsigned short* W1t; unsigned short* W2t; unsigned short* U; unsigned short* h1;
  unsigned* g;
  int N, E, NB, SB, S0, GMW;
};

// =================== persistent cooperative whole-network kernel ===================
__global__ __launch_bounds__(256, 3)
void k_net(Params P){
  cg::grid_group grid = cg::this_grid();
  const int tid = threadIdx.x;
  const int bid = blockIdx.x;
  const int nbk = gridDim.x;
  const int gtid = bid*256 + tid;
  const int gstride = nbk*256;

  __shared__ __align__(16) char smem[32768];
  __shared__ float sA[256], sB[256];
  __shared__ float scw[256], scb[256];
  __shared__ float srd[64];

  // ---- P0: weight transpose+convert, cnt=0, zero pad row of g ----
  for (int i = gtid; i < L_NUM*C_DIM*H_DIM; i += gstride){
    int l = i >> 15, r = i & 32767;
    { int k = r >> 8, n = r & 255;  P.W1t[l*32768 + n*128 + k] = f2bf(P.W1[i]); }
    { int k = r >> 7, n = r & 127;  P.W2t[l*32768 + n*256 + k] = f2bf(P.W2[i]); }
  }
  for (int i = gtid; i < P.N; i += gstride) P.cnt[i] = 0;
  if (gtid < 64) P.g[(size_t)P.N*64 + gtid] = 0u;
  grid.sync();

  // ---- P1: degree histogram ----
  for (int e = gtid; e < P.E; e += gstride) atomicAdd(P.cnt + P.dst[e], 1);
  grid.sync();

  // ---- P2: block-local exclusive scans ----
  {
    int* itmp = (int*)sA;
    for (int chunk = bid; chunk < P.SB; chunk += nbk){
      int i = chunk*256 + tid;
      int v = (i < P.N) ? P.cnt[i] : 0;
      __syncthreads();
      itmp[tid] = v; __syncthreads();
      for (int off = 1; off < 256; off <<= 1){
        int xv = (tid >= off) ? itmp[tid-off] : 0; __syncthreads();
        itmp[tid] += xv; __syncthreads();
      }
      if (i < P.N) P.rp[i] = itmp[tid] - v;
      if (tid == 255) P.bsum[chunk] = itmp[tid];
    }
  }
  grid.sync();

  // ---- P3: scan of block sums (single block; SB <= 256) ----
  if (bid == 0){
    int* itmp = (int*)sA;
    int v = (tid < P.SB) ? P.bsum[tid] : 0;
    itmp[tid] = v; __syncthreads();
    for (int off = 1; off < 256; off <<= 1){
      int xv = (tid >= off) ? itmp[tid-off] : 0; __syncthreads();
      itmp[tid] += xv; __syncthreads();
    }
    if (tid < P.SB) P.boff[tid] = itmp[tid] - v;
  }
  grid.sync();

  // ---- P4: add block offsets; reset cnt ----
  for (int i = gtid; i < P.N; i += gstride){ P.rp[i] += P.boff[i >> 8]; P.cnt[i] = 0; }
  if (gtid == 0) P.rp[P.N] = P.E;
  grid.sync();

  // ---- P5: scatter sources into CSR + layer-0 GN partial stats ----
  for (int e = gtid; e < P.E; e += gstride){
    int d = P.dst[e];
    int pos = P.rp[d] + atomicAdd(P.cnt + d, 1);
    P.csrc[pos] = P.src[e];
  }
  for (int chunk = bid; chunk < P.S0; chunk += nbk){
    int c = tid & 127, half = tid >> 7;
    int r0 = chunk*128, rend = min(r0 + 128, P.N);
    float s = 0.f, s2 = 0.f;
    for (int r = r0 + half; r < rend; r += 2){
      float v = P.x[r*C_DIM + c]; s += v; s2 += v*v;
    }
    __syncthreads();
    sA[tid] = s; sB[tid] = s2; __syncthreads();
    if (tid < 128){
      P.part[tid*P.NB + chunk]       = sA[tid] + sA[tid+128];
      P.part[(128+tid)*P.NB + chunk] = sB[tid] + sB[tid+128];
    }
  }
  grid.sync();

  // =================== layers ===================
  for (int l = 0; l < L_NUM; ++l){
    const float* Xin = (l == 0) ? P.x : P.xc;
    const bool lastL = (l == L_NUM - 1);
    const unsigned short* W1tl = P.W1t + (size_t)l*32768;
    const unsigned short* W2tl = P.W2t + (size_t)l*32768;
    const int npar = (l == 0) ? P.S0 : P.GMW;

    // ---- GN coef (pre-scaled by kk = t*log2e), one block per channel ----
    for (int c = bid; c < C_DIM; c += nbk){
      float s = 0.f, s2 = 0.f;
      for (int i = tid; i < npar; i += 256){
        s  += P.part[c*P.NB + i];
        s2 += P.part[(128+c)*P.NB + i];
      }
      __syncthreads();
      sA[tid] = s; sB[tid] = s2; __syncthreads();
      for (int off = 128; off; off >>= 1){
        if (tid < off){ sA[tid] += sA[tid+off]; sB[tid] += sB[tid+off]; }
        __syncthreads();
      }
      if (tid == 0){
        float kk = P.tpt[l] * 1.4426950408889634f;
        float inv = 1.f/(float)P.N;
        float mean = sA[0]*inv;
        float am = P.gna[l*C_DIM + c]*mean;
        float var = sB[0]*inv - 2.f*am*mean + am*am;
        float scale = P.gnw[l*C_DIM + c] * rsqrtf(var + 1e-5f);
        P.gncoef[c] = scale * kk;
        P.gncoef[128+c] = (P.gnb[l*C_DIM + c] - scale*am) * kk;
      }
    }
    grid.sync();

    // ---- gpre: g = kk*relu(affine(x)) in bf16 ----
    for (int i = gtid; i < P.N*32; i += gstride){
      int c4 = i & 31;
      float4 xv = ((const float4*)Xin)[i];
      float4 A = ((const float4*)P.gncoef)[c4];
      float4 B = ((const float4*)P.gncoef)[32 + c4];
      float o0 = fmaxf(A.x*xv.x + B.x, 0.f);
      float o1 = fmaxf(A.y*xv.y + B.y, 0.f);
      float o2 = fmaxf(A.z*xv.z + B.z, 0.f);
      float o3 = fmaxf(A.w*xv.w + B.w, 0.f);
      uint2 pk = make_uint2((unsigned)f2bf(o0) | ((unsigned)f2bf(o1) << 16),
                            (unsigned)f2bf(o2) | ((unsigned)f2bf(o3) << 16));
      ((uint2*)P.g)[i] = pk;
    }
    grid.sync();

    // ---- softmax aggregation (one wave per node; pad -> zero row) ----
    {
      const int wave = tid >> 6, lane = tid & 63;
      const float invkk = 1.f / (P.tpt[l] * 1.4426950408889634f);
      for (int n = bid*4 + wave; n < P.N; n += nbk*4){
        int jb = P.rp[n], je = P.rp[n+1];
        int deg = je - jb;
        int iters = (deg + 3) & ~3;
        float d0 = 0.f, d1 = 0.f, s0 = 0.f, s1 = 0.f;
        unsigned uo = P.g[(size_t)n*64 + lane];

        #define EDGE(uu) { \
          float p0 = __builtin_bit_cast(float, (uu) << 16); \
          float p1 = __builtin_bit_cast(float, (uu) & 0xffff0000u); \
          float e0 = exp2f(p0); \
          float e1 = exp2f(p1); \
          d0 += e0; d1 += e1; \
          s0 = fmaf(p0, e0, s0); s1 = fmaf(p1, e1, s1); }

        for (int base = jb; base < jb + iters; base += 64){
          int abs_e = base + lane;
          int myidx = (abs_e < je) ? P.csrc[abs_e] : P.N;
          int lim = min(64, jb + iters - base);       // multiple of 4
          for (int jj = 0; jj < lim; jj += 4){
            int i0 = __shfl(myidx, jj+0);
            int i1 = __shfl(myidx, jj+1);
            int i2 = __shfl(myidx, jj+2);
            int i3 = __shfl(myidx, jj+3);
            unsigned v0 = P.g[(size_t)i0*64 + lane];
            unsigned v1 = P.g[(size_t)i1*64 + lane];
            unsigned v2 = P.g[(size_t)i2*64 + lane];
            unsigned v3 = P.g[(size_t)i3*64 + lane];
            EDGE(v0); EDGE(v1); EDGE(v2); EDGE(v3);
          }
        }
        #undef EDGE

        float pad = (float)(iters - deg);
        d0 -= pad; d1 -= pad;
        float o0 = __builtin_bit_cast(float, uo << 16);
        float o1 = __builtin_bit_cast(float, uo & 0xffff0000u);
        float u0 = invkk * (s0/(d0 + 1e-16f) + o0) + 1e-7f;
        float u1 = invkk * (s1/(d1 + 1e-16f) + o1) + 1e-7f;
        unsigned pk = (unsigned)f2bf(u0) | ((unsigned)f2bf(u1) << 16);
        *(unsigned*)(P.U + (size_t)n*C_DIM + lane*2) = pk;
      }
    }
    grid.sync();

    // ---- GEMM1: h1(bf16) = U @ W1^T + b1 ; per-tile LN partials ----
    {
      const int wave = tid >> 6, lane = tid & 63;
      const int lr = lane & 15, lc = lane >> 4;
      for (int tile = bid; tile < P.GMW; tile += nbk){
        const int m0 = tile*64;
        __syncthreads();
        #pragma unroll
        for (int p = 0; p < 4; ++p){
          int idx = p*256 + tid;
          int row = idx >> 4, ch = idx & 15;
          int r = m0 + row;
          uint4 v = make_uint4(0u,0u,0u,0u);
          if (r < P.N) v = *(const uint4*)(P.U + (size_t)r*128 + ch*8);
          int o = (row*256 + ch*16) ^ ((row & 7) << 4);
          *(uint4*)(smem + o) = v;
        }
        __syncthreads();

        f32x4 acc[4][4] = {};
        #pragma unroll
        for (int ks = 0; ks < 4; ++ks){
          bf16x8 a[4];
          #pragma unroll
          for (int mf = 0; mf < 4; ++mf){
            int row = mf*16 + lr;
            int o = (row*256 + ks*64 + lc*16) ^ ((row & 7) << 4);
            a[mf] = *(const bf16x8*)(smem + o);
          }
          #pragma unroll
          for (int nf = 0; nf < 4; ++nf){
            int n = wave*64 + nf*16 + lr;
            bf16x8 bfrag = *(const bf16x8*)(W1tl + n*128 + ks*32 + lc*8);
            #pragma unroll
            for (int mf = 0; mf < 4; ++mf)
              acc[mf][nf] = __builtin_amdgcn_mfma_f32_16x16x32_bf16(a[mf], bfrag, acc[mf][nf], 0, 0, 0);
          }
        }

        float s1 = 0.f, s2 = 0.f;
        #pragma unroll
        for (int mf = 0; mf < 4; ++mf){
          #pragma unroll
          for (int j = 0; j < 4; ++j){
            int r = m0 + mf*16 + lc*4 + j;
            if (r < P.N){
              #pragma unroll
              for (int nf = 0; nf < 4; ++nf){
                int col = wave*64 + nf*16 + lr;
                float v = acc[mf][nf][j] + P.b1[l*H_DIM + col];
                P.h1[(size_t)r*H_DIM + col] = f2bf(v);
                s1 += v; s2 += v*v;
              }
            }
          }
        }
        #pragma unroll
        for (int o = 32; o; o >>= 1){ s1 += __shfl_down(s1, o); s2 += __shfl_down(s2, o); }
        if (lane == 0){ srd[wave] = s1; srd[4 + wave] = s2; }
        __syncthreads();
        if (tid == 0) P.lnpart[tile*2]     = srd[0]+srd[1]+srd[2]+srd[3];
        if (tid == 1) P.lnpart[tile*2 + 1] = srd[4]+srd[5]+srd[6]+srd[7];
      }
    }
    grid.sync();

    // ---- GEMM2: x_out = x_in + relu(LN(h1)) @ W2^T + b2 ; GN partials / final linear ----
    {
      const int wave = tid >> 6, lane = tid & 63;
      const int lr = lane & 15, lc = lane >> 4;
      for (int tile = bid; tile < P.GMW; tile += nbk){
        const int m0 = tile*64;
        __syncthreads();
        // block-local LN coefficient reduction (deterministic)
        {
          float s1 = 0.f, s2 = 0.f;
          for (int i = tid; i < P.GMW; i += 256){ s1 += P.lnpart[2*i]; s2 += P.lnpart[2*i+1]; }
          sA[tid] = s1; sB[tid] = s2; __syncthreads();
          for (int o = 128; o; o >>= 1){
            if (tid < o){ sA[tid] += sA[tid+o]; sB[tid] += sB[tid+o]; }
            __syncthreads();
          }
          double NH = (double)P.N * (double)H_DIM;
          double mean = (double)sA[0] / NH;
          double var = (double)sB[0] / NH - mean*mean;
          double sd = sqrt(var > 0.0 ? var : 0.0);
          float denom = (float)sd + 1e-5f;
          float wv = P.lnw[l*H_DIM + tid] / denom;
          scw[tid] = wv;
          scb[tid] = P.lnb[l*H_DIM + tid] - (float)mean * wv;
          if (tid < 64) srd[tid] = 0.f;
          __syncthreads();
        }
        #pragma unroll
        for (int p = 0; p < 8; ++p){
          int idx = (p*256 + tid)*8;
          int row = idx >> 8, col = idx & 255;
          int r = m0 + row;
          uint4 v = make_uint4(0u,0u,0u,0u);
          if (r < P.N) v = *(const uint4*)(P.h1 + (size_t)r*H_DIM + col);
          unsigned short hb[8] = {(unsigned short)(v.x&0xffff),(unsigned short)(v.x>>16),
                                  (unsigned short)(v.y&0xffff),(unsigned short)(v.y>>16),
                                  (unsigned short)(v.z&0xffff),(unsigned short)(v.z>>16),
                                  (unsigned short)(v.w&0xffff),(unsigned short)(v.w>>16)};
          unsigned outp[4];
          #pragma unroll
          for (int q = 0; q < 4; ++q){
            float f0 = fmaxf(scw[col+2*q]  *bf2f(hb[2*q])   + scb[col+2*q],   0.f);
            float f1 = fmaxf(scw[col+2*q+1]*bf2f(hb[2*q+1]) + scb[col+2*q+1], 0.f);
            outp[q] = (unsigned)f2bf(f0) | ((unsigned)f2bf(f1) << 16);
          }
          int o = (row*512 + col*2) ^ ((row & 7) << 4);
          *(uint4*)(smem + o) = make_uint4(outp[0],outp[1],outp[2],outp[3]);
        }
        __syncthreads();

        f32x4 acc[4][2] = {};
        #pragma unroll
        for (int ks = 0; ks < 8; ++ks){
          bf16x8 a[4];
          #pragma unroll
          for (int mf = 0; mf < 4; ++mf){
            int row = mf*16 + lr;
            int o = (row*512 + ks*64 + lc*16) ^ ((row & 7) << 4);
            a[mf] = *(const bf16x8*)(smem + o);
          }
          #pragma unroll
          for (int nf = 0; nf < 2; ++nf){
            int n = wave*32 + nf*16 + lr;
            bf16x8 bfrag = *(const bf16x8*)(W2tl + n*256 + ks*32 + lc*8);
            #pragma unroll
            for (int mf = 0; mf < 4; ++mf)
              acc[mf][nf] = __builtin_amdgcn_mfma_f32_16x16x32_bf16(a[mf], bfrag, acc[mf][nf], 0, 0, 0);
          }
        }

        float pA[2] = {0.f, 0.f}, pB[2] = {0.f, 0.f};
        #pragma unroll
        for (int mf = 0; mf < 4; ++mf){
          #pragma unroll
          for (int j = 0; j < 4; ++j){
            int r = m0 + mf*16 + lc*4 + j;
            if (r < P.N){
              float p = 0.f;
              #pragma unroll
              for (int nf = 0; nf < 2; ++nf){
                int col = wave*32 + nf*16 + lr;
                float v = Xin[(size_t)r*C_DIM + col] + acc[mf][nf][j] + P.b2[l*C_DIM + col];
                if (!lastL){
                  P.xc[(size_t)r*C_DIM + col] = v;
                  pA[nf] += v; pB[nf] += v*v;
                } else {
                  p += v * P.linw[col];
                }
              }
              if (lastL){
                p += __shfl_xor(p, 1); p += __shfl_xor(p, 2);
                p += __shfl_xor(p, 4); p += __shfl_xor(p, 8);
                if (lr == 0) atomicAdd(&srd[r - m0], p);
              }
            }
          }
        }
        if (!lastL){
          #pragma unroll
          for (int nf = 0; nf < 2; ++nf){
            pA[nf] += __shfl_xor(pA[nf], 16); pA[nf] += __shfl_xor(pA[nf], 32);
            pB[nf] += __shfl_xor(pB[nf], 16); pB[nf] += __shfl_xor(pB[nf], 32);
          }
          if (lane < 16){
            #pragma unroll
            for (int nf = 0; nf < 2; ++nf){
              int col = wave*32 + nf*16 + lr;
              P.part[col*P.NB + tile]       = pA[nf];
              P.part[(128+col)*P.NB + tile] = pB[nf];
            }
          }
        } else {
          __syncthreads();
          if (tid < 64 && m0 + tid < P.N) P.out[m0 + tid] = srd[tid] + P.linb[0];
        }
      }
    }
    grid.sync();
  }
}

// =================== fallback path (round-8 kernels) ===================
__global__ void k_hist(const int* __restrict__ dst, int* __restrict__ cnt, int E){
  for (int e = blockIdx.x*blockDim.x + threadIdx.x; e < E; e += gridDim.x*blockDim.x)
    atomicAdd(cnt + dst[e], 1);
}
__global__ void k_scan_local(const int* __restrict__ cnt, int* __restrict__ rp,
                             int* __restrict__ bsum, int N){
  __shared__ int tmp[256];
  int t = threadIdx.x; int i = blockIdx.x*256 + t;
  int v = (i < N) ? cnt[i] : 0;
  tmp[t] = v; __syncthreads();
  for (int off = 1; off < 256; off <<= 1){
    int x = (t >= off) ? tmp[t-off] : 0; __syncthreads();
    tmp[t] += x; __syncthreads();
  }
  if (i < N) rp[i] = tmp[t] - v;
  if (t == 255) bsum[blockIdx.x] = tmp[t];
}
__global__ void k_scan_bsums(const int* __restrict__ bsum, int* __restrict__ boff, int nb){
  __shared__ int tmp[256];
  int t = threadIdx.x;
  int v = (t < nb) ? bsum[t] : 0;
  tmp[t] = v; __syncthreads();
  for (int off = 1; off < 256; off <<= 1){
    int x = (t >= off) ? tmp[t-off] : 0; __syncthreads();
    tmp[t] += x; __syncthreads();
  }
  if (t < nb) boff[t] = tmp[t] - v;
}
__global__ void k_scan_add(int* __restrict__ rp, const int* __restrict__ boff, int N, int E){
  int i = blockIdx.x*256 + threadIdx.x;
  if (i < N) rp[i] += boff[blockIdx.x];
  if (i == 0) rp[N] = E;
}
__global__ void k_scatter(const int* __restrict__ src, const int* __restrict__ dst,
                          const int* __restrict__ rp, int* __restrict__ cnt,
                          int* __restrict__ csrc, int E){
  for (int e = blockIdx.x*blockDim.x + threadIdx.x; e < E; e += gridDim.x*blockDim.x){
    int d = dst[e];
    int pos = rp[d] + atomicAdd(cnt + d, 1);
    csrc[pos] = src[e];
  }
}
__global__ void k_wconv(const float* __restrict__ W1, const float* __restrict__ W2,
                        unsigned short* __restrict__ W1t, unsigned short* __restrict__ W2t,
                        unsigned* __restrict__ G, int N){
  int i = blockIdx.x*blockDim.x + threadIdx.x;
  if (blockIdx.x == 0 && threadIdx.x < 64) G[(size_t)N*64 + threadIdx.x] = 0u;
  if (i >= L_NUM*C_DIM*H_DIM) return;
  int l = i >> 15, r = i & 32767;
  { int k = r >> 8, n = r & 255;  W1t[l*32768 + n*128 + k] = f2bf(W1[i]); }
  { int k = r >> 7, n = r & 127;  W2t[l*32768 + n*256 + k] = f2bf(W2[i]); }
}
__global__ void k_stat0(const float* __restrict__ X, float* __restrict__ part, int NB, int N){
  int t = threadIdx.x; int c = t & 127; int half = t >> 7;
  int r0 = blockIdx.x*128, rend = min(r0 + 128, N);
  float s = 0.f, s2 = 0.f;
  for (int r = r0 + half; r < rend; r += 2){
    float v = X[r*C_DIM + c]; s += v; s2 += v*v;
  }
  __shared__ float a1[256], a2[256];
  a1[t] = s; a2[t] = s2; __syncthreads();
  if (t < 128){
    part[t*NB + blockIdx.x]       = a1[t] + a1[t+128];
    part[(128+t)*NB + blockIdx.x] = a2[t] + a2[t+128];
  }
}
__global__ void k_gn_coef(const float* __restrict__ part, int NB, int nb,
                          const float* __restrict__ gw, const float* __restrict__ gb,
                          const float* __restrict__ ga, const float* __restrict__ tptr, int l,
                          float* __restrict__ coef, int N){
  int c = blockIdx.x;
  int t = threadIdx.x;
  float s = 0.f, s2 = 0.f;
  for (int i = t; i < nb; i += 256){
    s  += part[c*NB + i];
    s2 += part[(128+c)*NB + i];
  }
  __shared__ float sh1[256], sh2[256];
  sh1[t] = s; sh2[t] = s2; __syncthreads();
  for (int off = 128; off; off >>= 1){
    if (t < off){ sh1[t] += sh1[t+off]; sh2[t] += sh2[t+off]; }
    __syncthreads();
  }
  if (t == 0){
    float kk = tptr[l] * 1.4426950408889634f;
    float inv = 1.f/(float)N;
    float mean = sh1[0]*inv;
    float am = ga[c]*mean;
    float var = sh2[0]*inv - 2.f*am*mean + am*am;
    float scale = gw[c] * rsqrtf(var + 1e-5f);
    coef[c] = scale * kk;
    coef[128+c] = (gb[c] - scale*am) * kk;
  }
}
__global__ void k_gpre(const float* __restrict__ X, const float* __restrict__ coef,
                       unsigned* __restrict__ G2, int total4){
  int i = blockIdx.x*blockDim.x + threadIdx.x;
  if (i >= total4) return;
  int c4 = i & 31;
  float4 x = ((const float4*)X)[i];
  float4 A = ((const float4*)coef)[c4];
  float4 B = ((const float4*)coef)[32 + c4];
  float o0 = fmaxf(A.x*x.x + B.x, 0.f);
  float o1 = fmaxf(A.y*x.y + B.y, 0.f);
  float o2 = fmaxf(A.z*x.z + B.z, 0.f);
  float o3 = fmaxf(A.w*x.w + B.w, 0.f);
  uint2 pk = make_uint2((unsigned)f2bf(o0) | ((unsigned)f2bf(o1) << 16),
                        (unsigned)f2bf(o2) | ((unsigned)f2bf(o3) << 16));
  ((uint2*)G2)[i] = pk;
}
__global__ void k_agg(const unsigned* __restrict__ G, const int* __restrict__ rp,
                      const int* __restrict__ csrc, const float* __restrict__ tptr, int l,
                      unsigned short* __restrict__ U, int N){
  int wave = threadIdx.x >> 6, lane = threadIdx.x & 63;
  int n = blockIdx.x*2 + wave;
  if (n >= N) return;
  float invkk = 1.f / (tptr[l] * 1.4426950408889634f);
  int jb = rp[n], je = rp[n+1];
  int deg = je - jb;
  int iters = (deg + 3) & ~3;
  float d0 = 0.f, d1 = 0.f, s0 = 0.f, s1 = 0.f;
  unsigned uo = G[(size_t)n*64 + lane];
  #define EDGE(uu) { \
    float p0 = __builtin_bit_cast(float, (uu) << 16); \
    float p1 = __builtin_bit_cast(float, (uu) & 0xffff0000u); \
    float e0 = exp2f(p0); \
    float e1 = exp2f(p1); \
    d0 += e0; d1 += e1; \
    s0 = fmaf(p0, e0, s0); s1 = fmaf(p1, e1, s1); }
  for (int base = jb; base < jb + iters; base += 64){
    int abs_e = base + lane;
    int myidx = (abs_e < je) ? csrc[abs_e] : N;
    int lim = min(64, jb + iters - base);
    for (int jj = 0; jj < lim; jj += 4){
      int i0 = __shfl(myidx, jj+0);
      int i1 = __shfl(myidx, jj+1);
      int i2 = __shfl(myidx, jj+2);
      int i3 = __shfl(myidx, jj+3);
      unsigned v0 = G[(size_t)i0*64 + lane];
      unsigned v1 = G[(size_t)i1*64 + lane];
      unsigned v2 = G[(size_t)i2*64 + lane];
      unsigned v3 = G[(size_t)i3*64 + lane];
      EDGE(v0); EDGE(v1); EDGE(v2); EDGE(v3);
    }
  }
  #undef EDGE
  float pad = (float)(iters - deg);
  d0 -= pad; d1 -= pad;
  float o0 = __builtin_bit_cast(float, uo << 16);
  float o1 = __builtin_bit_cast(float, uo & 0xffff0000u);
  float u0 = invkk * (s0/(d0 + 1e-16f) + o0) + 1e-7f;
  float u1 = invkk * (s1/(d1 + 1e-16f) + o1) + 1e-7f;
  unsigned pk = (unsigned)f2bf(u0) | ((unsigned)f2bf(u1) << 16);
  *(unsigned*)(U + n*C_DIM + lane*2) = pk;
}
__global__ void k_gemm1(const unsigned short* __restrict__ A, const unsigned short* __restrict__ Bt,
                        const float* __restrict__ b1, unsigned short* __restrict__ H1,
                        float* __restrict__ part, int M){
  __shared__ __align__(16) char smem[64*256];
  __shared__ float rbuf[8];
  const int tid = threadIdx.x;
  const int m0 = blockIdx.x * 64;
  const int wave = tid >> 6, lane = tid & 63;
  const int lr = lane & 15, lc = lane >> 4;
  bf16x8 bf[4][4];
  #pragma unroll
  for (int nf = 0; nf < 4; ++nf){
    int n = wave*64 + nf*16 + lr;
    #pragma unroll
    for (int ks = 0; ks < 4; ++ks)
      bf[nf][ks] = *(const bf16x8*)(Bt + n*128 + ks*32 + lc*8);
  }
  #pragma unroll
  for (int p = 0; p < 4; ++p){
    int idx = p*256 + tid;
    int row = idx >> 4, ch = idx & 15;
    int r = m0 + row;
    uint4 v = make_uint4(0u,0u,0u,0u);
    if (r < M) v = *(const uint4*)(A + r*128 + ch*8);
    int o = (row*256 + ch*16) ^ ((row & 7) << 4);
    *(uint4*)(smem + o) = v;
  }
  __syncthreads();
  f32x4 acc[4][4] = {};
  #pragma unroll
  for (int ks = 0; ks < 4; ++ks){
    bf16x8 a[4];
    #pragma unroll
    for (int mf = 0; mf < 4; ++mf){
      int row = mf*16 + lr;
      int o = (row*256 + ks*64 + lc*16) ^ ((row & 7) << 4);
      a[mf] = *(const bf16x8*)(smem + o);
    }
    #pragma unroll
    for (int mf = 0; mf < 4; ++mf)
      #pragma unroll
      for (int nf = 0; nf < 4; ++nf)
        acc[mf][nf] = __builtin_amdgcn_mfma_f32_16x16x32_bf16(a[mf], bf[nf][ks], acc[mf][nf], 0, 0, 0);
  }
  float s1 = 0.f, s2 = 0.f;
  #pragma unroll
  for (int mf = 0; mf < 4; ++mf){
    #pragma unroll
    for (int j = 0; j < 4; ++j){
      int r = m0 + mf*16 + lc*4 + j;
      if (r < M){
        #pragma unroll
        for (int nf = 0; nf < 4; ++nf){
          int col = wave*64 + nf*16 + lr;
          float v = acc[mf][nf][j] + b1[col];
          H1[r*H_DIM + col] = f2bf(v);
          s1 += v; s2 += v*v;
        }
      }
    }
  }
  #pragma unroll
  for (int o = 32; o; o >>= 1){ s1 += __shfl_down(s1, o); s2 += __shfl_down(s2, o); }
  if (lane == 0){ rbuf[wave] = s1; rbuf[4 + wave] = s2; }
  __syncthreads();
  if (tid == 0) part[blockIdx.x*2]     = rbuf[0]+rbuf[1]+rbuf[2]+rbuf[3];
  if (tid == 1) part[blockIdx.x*2 + 1] = rbuf[4]+rbuf[5]+rbuf[6]+rbuf[7];
}
__global__ void k_gemm2(const unsigned short* __restrict__ H1,
                        const float* __restrict__ lnpart, int nparts,
                        const float* __restrict__ lnw, const float* __restrict__ lnb,
                        const unsigned short* __restrict__ Bt, const float* __restrict__ b2,
                        const float* __restrict__ Xin, float* __restrict__ Xout,
                        float* __restrict__ part, int NB,
                        const float* __restrict__ lw, const float* __restrict__ lb,
                        float* __restrict__ out, int M){
  __shared__ __align__(16) char smem[64*512];
  __shared__ float red1[256], red2[256];
  __shared__ float colw[256], colb[256];
  __shared__ float rowdot[64];
  const int tid = threadIdx.x;
  const int m0 = blockIdx.x * 64;
  const int wave = tid >> 6, lane = tid & 63;
  const int lr = lane & 15, lc = lane >> 4;
  const bool last = (lw != nullptr);
  {
    float s1 = 0.f, s2 = 0.f;
    for (int i = tid; i < nparts; i += 256){ s1 += lnpart[2*i]; s2 += lnpart[2*i+1]; }
    red1[tid] = s1; red2[tid] = s2; __syncthreads();
    for (int o = 128; o; o >>= 1){
      if (tid < o){ red1[tid] += red1[tid+o]; red2[tid] += red2[tid+o]; }
      __syncthreads();
    }
    double NH = (double)M * (double)H_DIM;
    double mean = (double)red1[0] / NH;
    double var = (double)red2[0] / NH - mean*mean;
    double sd = sqrt(var > 0.0 ? var : 0.0);
    float denom = (float)sd + 1e-5f;
    float wv = lnw[tid] / denom;
    colw[tid] = wv;
    colb[tid] = lnb[tid] - (float)mean * wv;
    if (tid < 64) rowdot[tid] = 0.f;
    __syncthreads();
  }
  bf16x8 bf[2][8];
  #pragma unroll
  for (int nf = 0; nf < 2; ++nf){
    int n = wave*32 + nf*16 + lr;
    #pragma unroll
    for (int ks = 0; ks < 8; ++ks)
      bf[nf][ks] = *(const bf16x8*)(Bt + n*256 + ks*32 + lc*8);
  }
  #pragma unroll
  for (int p = 0; p < 8; ++p){
    int idx = (p*256 + tid)*8;
    int row = idx >> 8, col = idx & 255;
    int r = m0 + row;
    uint4 v = make_uint4(0u,0u,0u,0u);
    if (r < M) v = *(const uint4*)(H1 + r*H_DIM + col);
    unsigned short hb[8] = {(unsigned short)(v.x&0xffff),(unsigned short)(v.x>>16),
                            (unsigned short)(v.y&0xffff),(unsigned short)(v.y>>16),
                            (unsigned short)(v.z&0xffff),(unsigned short)(v.z>>16),
                            (unsigned short)(v.w&0xffff),(unsigned short)(v.w>>16)};
    unsigned outp[4];
    #pragma unroll
    for (int q = 0; q < 4; ++q){
      float f0 = fmaxf(colw[col+2*q]  *bf2f(hb[2*q])   + colb[col+2*q],   0.f);
      float f1 = fmaxf(colw[col+2*q+1]*bf2f(hb[2*q+1]) + colb[col+2*q+1], 0.f);
      outp[q] = (unsigned)f2bf(f0) | ((unsigned)f2bf(f1) << 16);
    }
    int o = (row*512 + col*2) ^ ((row & 7) << 4);
    *(uint4*)(smem + o) = make_uint4(outp[0],outp[1],outp[2],outp[3]);
  }
  __syncthreads();
  f32x4 acc[4][2] = {};
  #pragma unroll
  for (int ks = 0; ks < 8; ++ks){
    bf16x8 a[4];
    #pragma unroll
    for (int mf = 0; mf < 4; ++mf){
      int row = mf*16 + lr;
      int o = (row*512 + ks*64 + lc*16) ^ ((row & 7) << 4);
      a[mf] = *(const bf16x8*)(smem + o);
    }
    #pragma unroll
    for (int mf = 0; mf < 4; ++mf)
      #pragma unroll
      for (int nf = 0; nf < 2; ++nf)
        acc[mf][nf] = __builtin_amdgcn_mfma_f32_16x16x32_bf16(a[mf], bf[nf][ks], acc[mf][nf], 0, 0, 0);
  }
  float sA[2] = {0.f, 0.f}, sB[2] = {0.f, 0.f};
  #pragma unroll
  for (int mf = 0; mf < 4; ++mf){
    #pragma unroll
    for (int j = 0; j < 4; ++j){
      int r = m0 + mf*16 + lc*4 + j;
      if (r < M){
        float p = 0.f;
        #pragma unroll
        for (int nf = 0; nf < 2; ++nf){
          int col = wave*32 + nf*16 + lr;
          float v = Xin[r*C_DIM + col] + acc[mf][nf][j] + b2[col];
          if (!last){
            Xout[r*C_DIM + col] = v;
            sA[nf] += v; sB[nf] += v*v;
          } else {
            p += v * lw[col];
          }
        }
        if (last){
          p += __shfl_xor(p, 1); p += __shfl_xor(p, 2);
          p += __shfl_xor(p, 4); p += __shfl_xor(p, 8);
          if (lr == 0) atomicAdd(&rowdot[r - m0], p);
        }
      }
    }
  }
  if (!last){
    #pragma unroll
    for (int nf = 0; nf < 2; ++nf){
      sA[nf] += __shfl_xor(sA[nf], 16); sA[nf] += __shfl_xor(sA[nf], 32);
      sB[nf] += __shfl_xor(sB[nf], 16); sB[nf] += __shfl_xor(sB[nf], 32);
    }
    if (lane < 16){
      #pragma unroll
      for (int nf = 0; nf < 2; ++nf){
        int col = wave*32 + nf*16 + lr;
        part[col*NB + blockIdx.x]       = sA[nf];
        part[(128+col)*NB + blockIdx.x] = sB[nf];
      }
    }
  } else {
    __syncthreads();
    if (tid < 64 && m0 + tid < M) out[m0 + tid] = rowdot[tid] + lb[0];
  }
}

extern "C" void kernel_launch(void* const* d_in, const int* in_sizes, int n_in,
                              void* d_out, int out_size, void* d_ws, size_t ws_size,
                              hipStream_t stream){
  const float* x    = (const float*)d_in[0];
  const int*   src  = (const int*)d_in[1];
  const int*   dst  = (const int*)d_in[2];
  const float* W1   = (const float*)d_in[3];
  const float* b1   = (const float*)d_in[4];
  const float* lnw  = (const float*)d_in[5];
  const float* lnb  = (const float*)d_in[6];
  const float* W2   = (const float*)d_in[7];
  const float* b2   = (const float*)d_in[8];
  const float* tpt  = (const float*)d_in[9];
  const float* gnw  = (const float*)d_in[10];
  const float* gnb  = (const float*)d_in[11];
  const float* gna  = (const float*)d_in[12];
  const float* linw = (const float*)d_in[13];
  const float* linb = (const float*)d_in[14];
  (void)n_in; (void)out_size; (void)ws_size;
  const int N = in_sizes[0] / C_DIM;
  const int E = in_sizes[1];
  float* out = (float*)d_out;

  const int GMW = (N + 63)/64;
  const int S0  = (N + 127)/128;
  const int SB  = (N + 255)/256;
  const int NB  = GMW;

  char* wsp = (char*)d_ws; size_t off = 0;
  auto alloc = [&](size_t b)->char*{ char* p = wsp + off; off += (b + 255) & ~(size_t)255; return p; };
  int* cnt          = (int*)alloc((size_t)N*4);
  int* rp           = (int*)alloc((size_t)(N+1)*4);
  int* bsum         = (int*)alloc(1024);
  int* boff         = (int*)alloc(1024);
  float* gncoef     = (float*)alloc(1024);
  float* lnpart     = (float*)alloc((size_t)GMW*2*4);
  float* part       = (float*)alloc((size_t)NB*256*4);
  int* csrc         = (int*)alloc((size_t)E*4);
  unsigned short* W1t = (unsigned short*)alloc((size_t)L_NUM*C_DIM*H_DIM*2);
  unsigned short* W2t = (unsigned short*)alloc((size_t)L_NUM*C_DIM*H_DIM*2);
  unsigned* g       = (unsigned*)alloc((size_t)(N+1)*C_DIM*2);
  unsigned short* U = (unsigned short*)alloc((size_t)N*C_DIM*2);
  unsigned short* h1 = (unsigned short*)alloc((size_t)N*H_DIM*2);
  float* xc         = (float*)alloc((size_t)N*C_DIM*4);

  Params P;
  P.x = x; P.src = src; P.dst = dst;
  P.W1 = W1; P.b1 = b1; P.lnw = lnw; P.lnb = lnb;
  P.W2 = W2; P.b2 = b2; P.tpt = tpt;
  P.gnw = gnw; P.gnb = gnb; P.gna = gna;
  P.linw = linw; P.linb = linb; P.out = out;
  P.cnt = cnt; P.rp = rp; P.bsum = bsum; P.boff = boff; P.csrc = csrc;
  P.gncoef = gncoef; P.lnpart = lnpart; P.part = part; P.xc = xc;
  P.W1t = W1t; P.W2t = W2t; P.U = U; P.h1 = h1; P.g = g;
  P.N = N; P.E = E; P.NB = NB; P.SB = SB; P.S0 = S0; P.GMW = GMW;

  int maxb = 0;
  hipError_t qe = hipOccupancyMaxActiveBlocksPerMultiprocessor(&maxb, k_net, 256, 0);
  if (qe != hipSuccess || maxb < 1) maxb = 2;
  int grid = GMW < maxb*256 ? GMW : maxb*256;
  if (grid < 256) grid = 256;

  void* args[] = { &P };
  hipError_t ce = hipLaunchCooperativeKernel((void*)k_net, dim3(grid), dim3(256), args, 0, stream);
  if (ce != hipSuccess){
    // -------- fallback: round-8 multi-kernel path --------
    hipMemsetAsync(cnt, 0, (size_t)N*4, stream);
    k_hist<<<1024, 256, 0, stream>>>(dst, cnt, E);
    k_scan_local<<<SB, 256, 0, stream>>>(cnt, rp, bsum, N);
    k_scan_bsums<<<1, 256, 0, stream>>>(bsum, boff, SB);
    k_scan_add<<<SB, 256, 0, stream>>>(rp, boff, N, E);
    hipMemsetAsync(cnt, 0, (size_t)N*4, stream);
    k_scatter<<<1024, 256, 0, stream>>>(src, dst, rp, cnt, csrc, E);
    k_wconv<<<(L_NUM*C_DIM*H_DIM + 255)/256, 256, 0, stream>>>(W1, W2, W1t, W2t, g, N);
    k_stat0<<<S0, 256, 0, stream>>>(x, part, NB, N);
    for (int l = 0; l < L_NUM; ++l){
      int nbp = (l == 0) ? S0 : GMW;
      const float* Xin = (l == 0) ? x : xc;
      bool lastL = (l == L_NUM - 1);
      k_gn_coef<<<128, 256, 0, stream>>>(part, NB, nbp, gnw + l*C_DIM, gnb + l*C_DIM, gna + l*C_DIM, tpt, l, gncoef, N);
      k_gpre<<<(N*32 + 255)/256, 256, 0, stream>>>(Xin, gncoef, g, N*32);
      k_agg<<<(N + 1)/2, 128, 0, stream>>>(g, rp, csrc, tpt, l, U, N);
      k_gemm1<<<GMW, 256, 0, stream>>>(U, W1t + (size_t)l*C_DIM*H_DIM, b1 + l*H_DIM, h1, lnpart, N);
      k_gemm2<<<GMW, 256, 0, stream>>>(h1, lnpart, GMW, lnw + l*H_DIM, lnb + l*H_DIM,
                                       W2t + (size_t)l*C_DIM*H_DIM, b2 + l*C_DIM,
                                       Xin, xc, part, NB,
                                       lastL ? linw : nullptr, linb, out, N);
    }
  }
}

// Round 10
// 441.149 us; speedup vs baseline: 4.4349x; 4.4349x over previous
//
#include <hip/hip_runtime.h>

#define C_DIM 128
#define H_DIM 256
#define L_NUM 4

typedef __attribute__((ext_vector_type(8))) short bf16x8;
typedef __attribute__((ext_vector_type(4))) float f32x4;

__device__ __forceinline__ unsigned short f2bf(float f){
  unsigned u = __builtin_bit_cast(unsigned, f);
  u = u + 0x7FFFu + ((u >> 16) & 1u);   // round-to-nearest-even
  return (unsigned short)(u >> 16);
}
__device__ __forceinline__ float bf2f(unsigned short b){
  return __builtin_bit_cast(float, ((unsigned)b) << 16);
}
__device__ __forceinline__ float fexp2(float x){
#if __has_builtin(__builtin_amdgcn_exp2f)
  return __builtin_amdgcn_exp2f(x);      // single v_exp_f32
#else
  float r; asm("v_exp_f32 %0, %1" : "=v"(r) : "v"(x)); return r;
#endif
}

// ---------------- CSR build ----------------
__global__ void k_hist(const int* __restrict__ dst, int* __restrict__ cnt, int E){
  for (int e = blockIdx.x*blockDim.x + threadIdx.x; e < E; e += gridDim.x*blockDim.x)
    atomicAdd(cnt + dst[e], 1);
}

__global__ void k_scan_local(const int* __restrict__ cnt, int* __restrict__ rp,
                             int* __restrict__ bsum, int N){
  __shared__ int tmp[256];
  int t = threadIdx.x; int i = blockIdx.x*256 + t;
  int v = (i < N) ? cnt[i] : 0;
  tmp[t] = v; __syncthreads();
  for (int off = 1; off < 256; off <<= 1){
    int x = (t >= off) ? tmp[t-off] : 0; __syncthreads();
    tmp[t] += x; __syncthreads();
  }
  if (i < N) rp[i] = tmp[t] - v;              // exclusive within block
  if (t == 255) bsum[blockIdx.x] = tmp[t];
}

__global__ void k_scan_bsums(const int* __restrict__ bsum, int* __restrict__ boff, int nb){
  __shared__ int tmp[256];
  int t = threadIdx.x;
  int v = (t < nb) ? bsum[t] : 0;
  tmp[t] = v; __syncthreads();
  for (int off = 1; off < 256; off <<= 1){
    int x = (t >= off) ? tmp[t-off] : 0; __syncthreads();
    tmp[t] += x; __syncthreads();
  }
  if (t < nb) boff[t] = tmp[t] - v;           // exclusive
}

__global__ void k_scan_add(int* __restrict__ rp, const int* __restrict__ boff, int N, int E){
  int i = blockIdx.x*256 + threadIdx.x;
  if (i < N) rp[i] += boff[blockIdx.x];
  if (i == 0) rp[N] = E;
}

__global__ void k_scatter(const int* __restrict__ src, const int* __restrict__ dst,
                          const int* __restrict__ rp, int* __restrict__ cnt,
                          int* __restrict__ csrc, int E){
  for (int e = blockIdx.x*blockDim.x + threadIdx.x; e < E; e += gridDim.x*blockDim.x){
    int d = dst[e];
    int pos = rp[d] + atomicAdd(cnt + d, 1);
    csrc[pos] = src[e];
  }
}

// ---------------- weight transpose+convert ----------------
__global__ void k_wconv(const float* __restrict__ W1, const float* __restrict__ W2,
                        unsigned short* __restrict__ W1t, unsigned short* __restrict__ W2t){
  int i = blockIdx.x*blockDim.x + threadIdx.x;
  if (i >= L_NUM*C_DIM*H_DIM) return;
  int l = i >> 15, r = i & 32767;
  { int k = r >> 8, n = r & 255;  W1t[l*32768 + n*128 + k] = f2bf(W1[i]); }
  { int k = r >> 7, n = r & 127;  W2t[l*32768 + n*256 + k] = f2bf(W2[i]); }
}

// ---------------- layer-0 per-channel partial stats (column-major part[stat][NB]) --------
__global__ void k_stat0(const float* __restrict__ X, float* __restrict__ part, int NB, int N){
  int t = threadIdx.x; int c = t & 127; int half = t >> 7;
  int r0 = blockIdx.x*128, rend = min(r0 + 128, N);
  float s = 0.f, s2 = 0.f;
  for (int r = r0 + half; r < rend; r += 2){
    float v = X[r*C_DIM + c]; s += v; s2 += v*v;
  }
  __shared__ float a1[256], a2[256];
  a1[t] = s; a2[t] = s2; __syncthreads();
  if (t < 128){
    part[t*NB + blockIdx.x]       = a1[t] + a1[t+128];
    part[(128+t)*NB + blockIdx.x] = a2[t] + a2[t+128];
  }
}

// ---- graph norm: reduce partials + coef (pre-scaled by kk = t*log2(e)), 1 block/channel ----
__global__ void k_gn_coef(const float* __restrict__ part, int NB, int nb,
                          const float* __restrict__ gw, const float* __restrict__ gb,
                          const float* __restrict__ ga, const float* __restrict__ tptr, int l,
                          float* __restrict__ coef, int N){
  int c = blockIdx.x;       // 0..127
  int t = threadIdx.x;      // 256
  float s = 0.f, s2 = 0.f;
  for (int i = t; i < nb; i += 256){
    s  += part[c*NB + i];
    s2 += part[(128+c)*NB + i];
  }
  __shared__ float sh1[256], sh2[256];
  sh1[t] = s; sh2[t] = s2; __syncthreads();
  for (int off = 128; off; off >>= 1){
    if (t < off){ sh1[t] += sh1[t+off]; sh2[t] += sh2[t+off]; }
    __syncthreads();
  }
  if (t == 0){
    float kk = tptr[l] * 1.4426950408889634f;
    float inv = 1.f/(float)N;
    float mean = sh1[0]*inv;
    float am = ga[c]*mean;
    float var = sh2[0]*inv - 2.f*am*mean + am*am;   // E[(x - a*mean)^2]
    float scale = gw[c] * rsqrtf(var + 1e-5f);
    coef[c] = scale * kk;
    coef[128+c] = (gb[c] - scale*am) * kk;
  }
}

// ---------------- g = kk * relu(affine(x)) in bf16 (affine already kk-scaled) ----------------
__global__ void k_gpre(const float* __restrict__ X, const float* __restrict__ coef,
                       unsigned* __restrict__ G2, int total4){
  int i = blockIdx.x*blockDim.x + threadIdx.x;
  if (i >= total4) return;
  int c4 = i & 31;
  float4 x = ((const float4*)X)[i];
  float4 A = ((const float4*)coef)[c4];
  float4 B = ((const float4*)coef)[32 + c4];
  float o0 = fmaxf(A.x*x.x + B.x, 0.f);
  float o1 = fmaxf(A.y*x.y + B.y, 0.f);
  float o2 = fmaxf(A.z*x.z + B.z, 0.f);
  float o3 = fmaxf(A.w*x.w + B.w, 0.f);
  uint2 pk = make_uint2((unsigned)f2bf(o0) | ((unsigned)f2bf(o1) << 16),
                        (unsigned)f2bf(o2) | ((unsigned)f2bf(o3) << 16));
  ((uint2*)G2)[i] = pk;
}

// ---- softmax aggregation: G holds p = kk*g; e = 2^p via native v_exp_f32; guarded tail ----
__global__ void k_agg(const unsigned* __restrict__ G, const int* __restrict__ rp,
                      const int* __restrict__ csrc, const float* __restrict__ tptr, int l,
                      unsigned short* __restrict__ U, int N){
  int wave = threadIdx.x >> 6, lane = threadIdx.x & 63;
  int n = blockIdx.x*4 + wave;
  if (n >= N) return;
  float invkk = 1.f / (tptr[l] * 1.4426950408889634f);
  int jb = rp[n], je = rp[n+1];
  float d0 = 0.f, d1 = 0.f, s0 = 0.f, s1 = 0.f;
  unsigned uo = G[(size_t)n*64 + lane];   // self row, prefetched

  #define EDGE(uu) { \
    float p0 = __builtin_bit_cast(float, (uu) << 16); \
    float p1 = __builtin_bit_cast(float, (uu) & 0xffff0000u); \
    float e0 = fexp2(p0); \
    float e1 = fexp2(p1); \
    d0 += e0; d1 += e1; \
    s0 = fmaf(p0, e0, s0); s1 = fmaf(p1, e1, s1); }

  for (int base = jb; base < je; base += 64){
    int cnt = min(64, je - base);
    int myidx = (base + lane < je) ? csrc[base + lane] : 0;
    int jj = 0;
    for (; jj + 3 < cnt; jj += 4){
      int i0 = __shfl(myidx, jj);
      int i1 = __shfl(myidx, jj+1);
      int i2 = __shfl(myidx, jj+2);
      int i3 = __shfl(myidx, jj+3);
      unsigned v0 = G[(size_t)i0*64 + lane];
      unsigned v1 = G[(size_t)i1*64 + lane];
      unsigned v2 = G[(size_t)i2*64 + lane];
      unsigned v3 = G[(size_t)i3*64 + lane];
      EDGE(v0); EDGE(v1); EDGE(v2); EDGE(v3);
    }
    for (; jj < cnt; ++jj){
      unsigned u = G[(size_t)__shfl(myidx, jj)*64 + lane];
      EDGE(u);
    }
  }
  #undef EDGE

  float o0 = __builtin_bit_cast(float, uo << 16);
  float o1 = __builtin_bit_cast(float, uo & 0xffff0000u);
  float u0 = invkk * (s0/(d0 + 1e-16f) + o0) + 1e-7f;
  float u1 = invkk * (s1/(d1 + 1e-16f) + o1) + 1e-7f;
  unsigned pk = (unsigned)f2bf(u0) | ((unsigned)f2bf(u1) << 16);
  *(unsigned*)(U + n*C_DIM + lane*2) = pk;
}

// ---------------- GEMM1: h1(bf16) = U(bf16)[M,128] @ W1t^T + b1 ; per-block LN partials ----
__global__ void k_gemm1(const unsigned short* __restrict__ A, const unsigned short* __restrict__ Bt,
                        const float* __restrict__ b1, unsigned short* __restrict__ H1,
                        float* __restrict__ part, int M){
  __shared__ __align__(16) char smem[64*256];   // 64 rows x 128 bf16 (256B rows), swizzled
  __shared__ float rbuf[8];
  const int tid = threadIdx.x;
  const int m0 = blockIdx.x * 64;
  const int wave = tid >> 6, lane = tid & 63;
  const int lr = lane & 15, lc = lane >> 4;

  bf16x8 bf[4][4];
  #pragma unroll
  for (int nf = 0; nf < 4; ++nf){
    int n = wave*64 + nf*16 + lr;
    #pragma unroll
    for (int ks = 0; ks < 4; ++ks)
      bf[nf][ks] = *(const bf16x8*)(Bt + n*128 + ks*32 + lc*8);
  }
  #pragma unroll
  for (int p = 0; p < 4; ++p){
    int idx = p*256 + tid;
    int row = idx >> 4, ch = idx & 15;
    int r = m0 + row;
    uint4 v = make_uint4(0u,0u,0u,0u);
    if (r < M) v = *(const uint4*)(A + r*128 + ch*8);
    int o = (row*256 + ch*16) ^ ((row & 7) << 4);
    *(uint4*)(smem + o) = v;
  }
  __syncthreads();

  f32x4 acc[4][4] = {};
  #pragma unroll
  for (int ks = 0; ks < 4; ++ks){
    bf16x8 a[4];
    #pragma unroll
    for (int mf = 0; mf < 4; ++mf){
      int row = mf*16 + lr;
      int o = (row*256 + ks*64 + lc*16) ^ ((row & 7) << 4);
      a[mf] = *(const bf16x8*)(smem + o);
    }
    #pragma unroll
    for (int mf = 0; mf < 4; ++mf)
      #pragma unroll
      for (int nf = 0; nf < 4; ++nf)
        acc[mf][nf] = __builtin_amdgcn_mfma_f32_16x16x32_bf16(a[mf], bf[nf][ks], acc[mf][nf], 0, 0, 0);
  }

  float s1 = 0.f, s2 = 0.f;
  #pragma unroll
  for (int mf = 0; mf < 4; ++mf){
    #pragma unroll
    for (int j = 0; j < 4; ++j){
      int r = m0 + mf*16 + lc*4 + j;
      if (r < M){
        #pragma unroll
        for (int nf = 0; nf < 4; ++nf){
          int col = wave*64 + nf*16 + lr;
          float v = acc[mf][nf][j] + b1[col];
          H1[r*H_DIM + col] = f2bf(v);
          s1 += v; s2 += v*v;
        }
      }
    }
  }
  #pragma unroll
  for (int o = 32; o; o >>= 1){ s1 += __shfl_down(s1, o); s2 += __shfl_down(s2, o); }
  if (lane == 0){ rbuf[wave] = s1; rbuf[4 + wave] = s2; }
  __syncthreads();
  if (tid == 0)
    part[blockIdx.x*2]     = rbuf[0]+rbuf[1]+rbuf[2]+rbuf[3];
  if (tid == 1)
    part[blockIdx.x*2 + 1] = rbuf[4]+rbuf[5]+rbuf[6]+rbuf[7];
}

// ---- GEMM2: x_out = x_in + relu(LN(H1))(bf16) @ W2t^T + b2 ; LN coef block-local;
//      writes next-layer GN partials; last layer: fused final linear to out --------------
__global__ void k_gemm2(const unsigned short* __restrict__ H1,
                        const float* __restrict__ lnpart, int nparts,
                        const float* __restrict__ lnw, const float* __restrict__ lnb,
                        const unsigned short* __restrict__ Bt, const float* __restrict__ b2,
                        const float* __restrict__ Xin, float* __restrict__ Xout,
                        float* __restrict__ part, int NB,
                        const float* __restrict__ lw, const float* __restrict__ lb,
                        float* __restrict__ out, int M){
  __shared__ __align__(16) char smem[64*512];   // 64 rows x 256 bf16 (512B rows), swizzled
  __shared__ float red1[256], red2[256];
  __shared__ float colw[256], colb[256];
  __shared__ float rowdot[64];
  const int tid = threadIdx.x;
  const int m0 = blockIdx.x * 64;
  const int wave = tid >> 6, lane = tid & 63;
  const int lr = lane & 15, lc = lane >> 4;
  const bool last = (lw != nullptr);

  // ---- LN coefficients (block-local deterministic reduction of lnpart) ----
  {
    float s1 = 0.f, s2 = 0.f;
    for (int i = tid; i < nparts; i += 256){ s1 += lnpart[2*i]; s2 += lnpart[2*i+1]; }
    red1[tid] = s1; red2[tid] = s2; __syncthreads();
    for (int o = 128; o; o >>= 1){
      if (tid < o){ red1[tid] += red1[tid+o]; red2[tid] += red2[tid+o]; }
      __syncthreads();
    }
    double NH = (double)M * (double)H_DIM;
    double mean = (double)red1[0] / NH;
    double var = (double)red2[0] / NH - mean*mean;
    double sd = sqrt(var > 0.0 ? var : 0.0);
    float denom = (float)sd + 1e-5f;
    float wv = lnw[tid] / denom;
    colw[tid] = wv;
    colb[tid] = lnb[tid] - (float)mean * wv;
    if (tid < 64) rowdot[tid] = 0.f;
    __syncthreads();
  }

  bf16x8 bf[2][8];
  #pragma unroll
  for (int nf = 0; nf < 2; ++nf){
    int n = wave*32 + nf*16 + lr;
    #pragma unroll
    for (int ks = 0; ks < 8; ++ks)
      bf[nf][ks] = *(const bf16x8*)(Bt + n*256 + ks*32 + lc*8);
  }
  #pragma unroll
  for (int p = 0; p < 8; ++p){
    int idx = (p*256 + tid)*8;
    int row = idx >> 8, col = idx & 255;
    int r = m0 + row;
    uint4 v = make_uint4(0u,0u,0u,0u);
    if (r < M) v = *(const uint4*)(H1 + r*H_DIM + col);
    unsigned short hb[8] = {(unsigned short)(v.x&0xffff),(unsigned short)(v.x>>16),
                            (unsigned short)(v.y&0xffff),(unsigned short)(v.y>>16),
                            (unsigned short)(v.z&0xffff),(unsigned short)(v.z>>16),
                            (unsigned short)(v.w&0xffff),(unsigned short)(v.w>>16)};
    unsigned outp[4];
    #pragma unroll
    for (int q = 0; q < 4; ++q){
      float f0 = fmaxf(colw[col+2*q]  *bf2f(hb[2*q])   + colb[col+2*q],   0.f);
      float f1 = fmaxf(colw[col+2*q+1]*bf2f(hb[2*q+1]) + colb[col+2*q+1], 0.f);
      outp[q] = (unsigned)f2bf(f0) | ((unsigned)f2bf(f1) << 16);
    }
    int o = (row*512 + col*2) ^ ((row & 7) << 4);
    *(uint4*)(smem + o) = make_uint4(outp[0],outp[1],outp[2],outp[3]);
  }
  __syncthreads();

  f32x4 acc[4][2] = {};
  #pragma unroll
  for (int ks = 0; ks < 8; ++ks){
    bf16x8 a[4];
    #pragma unroll
    for (int mf = 0; mf < 4; ++mf){
      int row = mf*16 + lr;
      int o = (row*512 + ks*64 + lc*16) ^ ((row & 7) << 4);
      a[mf] = *(const bf16x8*)(smem + o);
    }
    #pragma unroll
    for (int mf = 0; mf < 4; ++mf)
      #pragma unroll
      for (int nf = 0; nf < 2; ++nf)
        acc[mf][nf] = __builtin_amdgcn_mfma_f32_16x16x32_bf16(a[mf], bf[nf][ks], acc[mf][nf], 0, 0, 0);
  }

  float sA[2] = {0.f, 0.f}, sB[2] = {0.f, 0.f};
  #pragma unroll
  for (int mf = 0; mf < 4; ++mf){
    #pragma unroll
    for (int j = 0; j < 4; ++j){
      int r = m0 + mf*16 + lc*4 + j;
      if (r < M){
        float p = 0.f;
        #pragma unroll
        for (int nf = 0; nf < 2; ++nf){
          int col = wave*32 + nf*16 + lr;
          float v = Xin[r*C_DIM + col] + acc[mf][nf][j] + b2[col];
          if (!last){
            Xout[r*C_DIM + col] = v;
            sA[nf] += v; sB[nf] += v*v;
          } else {
            p += v * lw[col];
          }
        }
        if (last){
          p += __shfl_xor(p, 1); p += __shfl_xor(p, 2);
          p += __shfl_xor(p, 4); p += __shfl_xor(p, 8);
          if (lr == 0) atomicAdd(&rowdot[r - m0], p);
        }
      }
    }
  }
  if (!last){
    #pragma unroll
    for (int nf = 0; nf < 2; ++nf){
      sA[nf] += __shfl_xor(sA[nf], 16); sA[nf] += __shfl_xor(sA[nf], 32);
      sB[nf] += __shfl_xor(sB[nf], 16); sB[nf] += __shfl_xor(sB[nf], 32);
    }
    if (lane < 16){
      #pragma unroll
      for (int nf = 0; nf < 2; ++nf){
        int col = wave*32 + nf*16 + lr;
        part[col*NB + blockIdx.x]       = sA[nf];
        part[(128+col)*NB + blockIdx.x] = sB[nf];
      }
    }
  } else {
    __syncthreads();
    if (tid < 64 && m0 + tid < M) out[m0 + tid] = rowdot[tid] + lb[0];
  }
}

extern "C" void kernel_launch(void* const* d_in, const int* in_sizes, int n_in,
                              void* d_out, int out_size, void* d_ws, size_t ws_size,
                              hipStream_t stream){
  const float* x    = (const float*)d_in[0];
  const int*   src  = (const int*)d_in[1];
  const int*   dst  = (const int*)d_in[2];
  const float* W1   = (const float*)d_in[3];
  const float* b1   = (const float*)d_in[4];
  const float* lnw  = (const float*)d_in[5];
  const float* lnb  = (const float*)d_in[6];
  const float* W2   = (const float*)d_in[7];
  const float* b2   = (const float*)d_in[8];
  const float* tpt  = (const float*)d_in[9];
  const float* gnw  = (const float*)d_in[10];
  const float* gnb  = (const float*)d_in[11];
  const float* gna  = (const float*)d_in[12];
  const float* linw = (const float*)d_in[13];
  const float* linb = (const float*)d_in[14];
  (void)n_in; (void)out_size; (void)ws_size;
  const int N = in_sizes[0] / C_DIM;
  const int E = in_sizes[1];
  float* out = (float*)d_out;

  const int gmw = (N + 63)/64;          // gemm blocks (64 rows each)
  const int S0  = (N + 127)/128;        // stat0 blocks
  const int NB  = gmw;                  // partial-stat stride

  char* wsp = (char*)d_ws; size_t off = 0;
  auto alloc = [&](size_t b)->char*{ char* p = wsp + off; off += (b + 255) & ~(size_t)255; return p; };
  int* cnt          = (int*)alloc((size_t)N*4);
  int* rp           = (int*)alloc((size_t)(N+1)*4);
  int* bsum         = (int*)alloc(1024);
  int* boff         = (int*)alloc(1024);
  float* gncoef     = (float*)alloc(1024);
  float* lnpart     = (float*)alloc((size_t)gmw*2*4);
  float* part       = (float*)alloc((size_t)NB*256*4);   // column-major per-block GN partials
  int* csrc         = (int*)alloc((size_t)E*4);
  unsigned short* W1t = (unsigned short*)alloc((size_t)L_NUM*C_DIM*H_DIM*2);
  unsigned short* W2t = (unsigned short*)alloc((size_t)L_NUM*C_DIM*H_DIM*2);
  unsigned* g       = (unsigned*)alloc((size_t)N*C_DIM*2);   // bf16 [N][128]
  unsigned short* U = (unsigned short*)alloc((size_t)N*C_DIM*2);
  unsigned short* h1 = (unsigned short*)alloc((size_t)N*H_DIM*2);
  float* xc         = (float*)alloc((size_t)N*C_DIM*4);

  const int SB = (N + 255)/256;
  hipMemsetAsync(cnt, 0, (size_t)N*4, stream);
  k_hist<<<1024, 256, 0, stream>>>(dst, cnt, E);
  k_scan_local<<<SB, 256, 0, stream>>>(cnt, rp, bsum, N);
  k_scan_bsums<<<1, 256, 0, stream>>>(bsum, boff, SB);
  k_scan_add<<<SB, 256, 0, stream>>>(rp, boff, N, E);
  hipMemsetAsync(cnt, 0, (size_t)N*4, stream);
  k_scatter<<<1024, 256, 0, stream>>>(src, dst, rp, cnt, csrc, E);
  k_wconv<<<(L_NUM*C_DIM*H_DIM + 255)/256, 256, 0, stream>>>(W1, W2, W1t, W2t);
  k_stat0<<<S0, 256, 0, stream>>>(x, part, NB, N);

  for (int l = 0; l < L_NUM; ++l){
    int nb = (l == 0) ? S0 : gmw;
    const float* Xin = (l == 0) ? x : xc;
    bool lastL = (l == L_NUM - 1);
    k_gn_coef<<<128, 256, 0, stream>>>(part, NB, nb, gnw + l*C_DIM, gnb + l*C_DIM, gna + l*C_DIM, tpt, l, gncoef, N);
    k_gpre<<<(N*32 + 255)/256, 256, 0, stream>>>(Xin, gncoef, g, N*32);
    k_agg<<<(N + 3)/4, 256, 0, stream>>>(g, rp, csrc, tpt, l, U, N);
    k_gemm1<<<gmw, 256, 0, stream>>>(U, W1t + (size_t)l*C_DIM*H_DIM, b1 + l*H_DIM, h1, lnpart, N);
    k_gemm2<<<gmw, 256, 0, stream>>>(h1, lnpart, gmw, lnw + l*H_DIM, lnb + l*H_DIM,
                                     W2t + (size_t)l*C_DIM*H_DIM, b2 + l*C_DIM,
                                     Xin, xc, part, NB,
                                     lastL ? linw : nullptr, linb, out, N);
  }
}

// Round 11
// 430.928 us; speedup vs baseline: 4.5400x; 1.0237x over previous
//
#include <hip/hip_runtime.h>

#define C_DIM 128
#define H_DIM 256
#define L_NUM 4

typedef __attribute__((ext_vector_type(8))) short bf16x8;
typedef __attribute__((ext_vector_type(4))) float f32x4;

__device__ __forceinline__ unsigned short f2bf(float f){
  unsigned u = __builtin_bit_cast(unsigned, f);
  u = u + 0x7FFFu + ((u >> 16) & 1u);   // round-to-nearest-even
  return (unsigned short)(u >> 16);
}
__device__ __forceinline__ float bf2f(unsigned short b){
  return __builtin_bit_cast(float, ((unsigned)b) << 16);
}
__device__ __forceinline__ float fexp2(float x){
#if __has_builtin(__builtin_amdgcn_exp2f)
  return __builtin_amdgcn_exp2f(x);      // single v_exp_f32
#else
  float r; asm("v_exp_f32 %0, %1" : "=v"(r) : "v"(x)); return r;
#endif
}

// ---- merged preamble: wconv (512 blocks) | stat0 (S0 blocks) | hist (rest) ----
__global__ void k_pre(const float* __restrict__ W1, const float* __restrict__ W2,
                      unsigned short* __restrict__ W1t, unsigned short* __restrict__ W2t,
                      const float* __restrict__ X, float* __restrict__ part, int NB,
                      const int* __restrict__ dst, int* __restrict__ cnt,
                      int N, int E, int S0){
  __shared__ float a1[256], a2[256];
  int b = blockIdx.x;
  if (b < 512){
    int i = b*256 + threadIdx.x;            // 512*256 == L*C*H exactly
    int l = i >> 15, r = i & 32767;
    { int k = r >> 8, n = r & 255;  W1t[l*32768 + n*128 + k] = f2bf(W1[i]); }
    { int k = r >> 7, n = r & 127;  W2t[l*32768 + n*256 + k] = f2bf(W2[i]); }
  } else if (b < 512 + S0){
    int chunk = b - 512;
    int t = threadIdx.x; int c = t & 127; int half = t >> 7;
    int r0 = chunk*128, rend = min(r0 + 128, N);
    float s = 0.f, s2 = 0.f;
    for (int r = r0 + half; r < rend; r += 2){
      float v = X[r*C_DIM + c]; s += v; s2 += v*v;
    }
    a1[t] = s; a2[t] = s2; __syncthreads();
    if (t < 128){
      part[t*NB + chunk]       = a1[t] + a1[t+128];
      part[(128+t)*NB + chunk] = a2[t] + a2[t+128];
    }
  } else {
    int nb = gridDim.x - 512 - S0;
    int bb = b - 512 - S0;
    for (int e = bb*256 + threadIdx.x; e < E; e += nb*256)
      atomicAdd(cnt + dst[e], 1);
  }
}

__global__ void k_scan_local(const int* __restrict__ cnt, int* __restrict__ rp,
                             int* __restrict__ bsum, int N){
  __shared__ int tmp[256];
  int t = threadIdx.x; int i = blockIdx.x*256 + t;
  int v = (i < N) ? cnt[i] : 0;
  tmp[t] = v; __syncthreads();
  for (int off = 1; off < 256; off <<= 1){
    int x = (t >= off) ? tmp[t-off] : 0; __syncthreads();
    tmp[t] += x; __syncthreads();
  }
  if (i < N) rp[i] = tmp[t] - v;              // exclusive within block
  if (t == 255) bsum[blockIdx.x] = tmp[t];
}

__global__ void k_scan_bsums(const int* __restrict__ bsum, int* __restrict__ boff, int nb){
  __shared__ int tmp[256];
  int t = threadIdx.x;
  int v = (t < nb) ? bsum[t] : 0;
  tmp[t] = v; __syncthreads();
  for (int off = 1; off < 256; off <<= 1){
    int x = (t >= off) ? tmp[t-off] : 0; __syncthreads();
    tmp[t] += x; __syncthreads();
  }
  if (t < nb) boff[t] = tmp[t] - v;           // exclusive
}

// adds block offsets AND re-zeros cnt for the scatter pass
__global__ void k_scan_add(int* __restrict__ rp, const int* __restrict__ boff,
                           int* __restrict__ cnt, int N, int E){
  int i = blockIdx.x*256 + threadIdx.x;
  if (i < N){ rp[i] += boff[blockIdx.x]; cnt[i] = 0; }
  if (i == 0) rp[N] = E;
}

__global__ void k_scatter(const int* __restrict__ src, const int* __restrict__ dst,
                          const int* __restrict__ rp, int* __restrict__ cnt,
                          int* __restrict__ csrc, int E){
  for (int e = blockIdx.x*blockDim.x + threadIdx.x; e < E; e += gridDim.x*blockDim.x){
    int d = dst[e];
    int pos = rp[d] + atomicAdd(cnt + d, 1);
    csrc[pos] = src[e];
  }
}

// ---- graph norm: reduce partials + coef (pre-scaled by kk = t*log2(e)), 1 block/channel ----
__global__ void k_gn_coef(const float* __restrict__ part, int NB, int nb,
                          const float* __restrict__ gw, const float* __restrict__ gb,
                          const float* __restrict__ ga, const float* __restrict__ tptr, int l,
                          float* __restrict__ coef, int N){
  int c = blockIdx.x;       // 0..127
  int t = threadIdx.x;      // 256
  float s = 0.f, s2 = 0.f;
  for (int i = t; i < nb; i += 256){
    s  += part[c*NB + i];
    s2 += part[(128+c)*NB + i];
  }
  __shared__ float sh1[256], sh2[256];
  sh1[t] = s; sh2[t] = s2; __syncthreads();
  for (int off = 128; off; off >>= 1){
    if (t < off){ sh1[t] += sh1[t+off]; sh2[t] += sh2[t+off]; }
    __syncthreads();
  }
  if (t == 0){
    float kk = tptr[l] * 1.4426950408889634f;
    float inv = 1.f/(float)N;
    float mean = sh1[0]*inv;
    float am = ga[c]*mean;
    float var = sh2[0]*inv - 2.f*am*mean + am*am;   // E[(x - a*mean)^2]
    float scale = gw[c] * rsqrtf(var + 1e-5f);
    coef[c] = scale * kk;
    coef[128+c] = (gb[c] - scale*am) * kk;
  }
}

// ---------------- g = kk * relu(affine(x)) in bf16 (affine already kk-scaled) ----------------
__global__ void k_gpre(const float* __restrict__ X, const float* __restrict__ coef,
                       unsigned* __restrict__ G2, int total4){
  int i = blockIdx.x*blockDim.x + threadIdx.x;
  if (i >= total4) return;
  int c4 = i & 31;
  float4 x = ((const float4*)X)[i];
  float4 A = ((const float4*)coef)[c4];
  float4 B = ((const float4*)coef)[32 + c4];
  float o0 = fmaxf(A.x*x.x + B.x, 0.f);
  float o1 = fmaxf(A.y*x.y + B.y, 0.f);
  float o2 = fmaxf(A.z*x.z + B.z, 0.f);
  float o3 = fmaxf(A.w*x.w + B.w, 0.f);
  uint2 pk = make_uint2((unsigned)f2bf(o0) | ((unsigned)f2bf(o1) << 16),
                        (unsigned)f2bf(o2) | ((unsigned)f2bf(o3) << 16));
  ((uint2*)G2)[i] = pk;
}

// ---- softmax aggregation: 2 nodes per 128-thread block (better Poisson balance) ----
__global__ void k_agg(const unsigned* __restrict__ G, const int* __restrict__ rp,
                      const int* __restrict__ csrc, const float* __restrict__ tptr, int l,
                      unsigned short* __restrict__ U, int N){
  int wave = threadIdx.x >> 6, lane = threadIdx.x & 63;
  int n = blockIdx.x*2 + wave;
  if (n >= N) return;
  float invkk = 1.f / (tptr[l] * 1.4426950408889634f);
  int jb = rp[n], je = rp[n+1];
  float d0 = 0.f, d1 = 0.f, s0 = 0.f, s1 = 0.f;
  unsigned uo = G[(size_t)n*64 + lane];   // self row, prefetched

  #define EDGE(uu) { \
    float p0 = __builtin_bit_cast(float, (uu) << 16); \
    float p1 = __builtin_bit_cast(float, (uu) & 0xffff0000u); \
    float e0 = fexp2(p0); \
    float e1 = fexp2(p1); \
    d0 += e0; d1 += e1; \
    s0 = fmaf(p0, e0, s0); s1 = fmaf(p1, e1, s1); }

  for (int base = jb; base < je; base += 64){
    int cnt = min(64, je - base);
    int myidx = (base + lane < je) ? csrc[base + lane] : 0;
    int jj = 0;
    for (; jj + 3 < cnt; jj += 4){
      int i0 = __shfl(myidx, jj);
      int i1 = __shfl(myidx, jj+1);
      int i2 = __shfl(myidx, jj+2);
      int i3 = __shfl(myidx, jj+3);
      unsigned v0 = G[(size_t)i0*64 + lane];
      unsigned v1 = G[(size_t)i1*64 + lane];
      unsigned v2 = G[(size_t)i2*64 + lane];
      unsigned v3 = G[(size_t)i3*64 + lane];
      EDGE(v0); EDGE(v1); EDGE(v2); EDGE(v3);
    }
    for (; jj < cnt; ++jj){
      unsigned u = G[(size_t)__shfl(myidx, jj)*64 + lane];
      EDGE(u);
    }
  }
  #undef EDGE

  float o0 = __builtin_bit_cast(float, uo << 16);
  float o1 = __builtin_bit_cast(float, uo & 0xffff0000u);
  float u0 = invkk * (s0/(d0 + 1e-16f) + o0) + 1e-7f;
  float u1 = invkk * (s1/(d1 + 1e-16f) + o1) + 1e-7f;
  unsigned pk = (unsigned)f2bf(u0) | ((unsigned)f2bf(u1) << 16);
  *(unsigned*)(U + n*C_DIM + lane*2) = pk;
}

// ---------------- GEMM1: h1(bf16) = U(bf16)[M,128] @ W1t^T + b1 ; per-block LN partials ----
__global__ void k_gemm1(const unsigned short* __restrict__ A, const unsigned short* __restrict__ Bt,
                        const float* __restrict__ b1, unsigned short* __restrict__ H1,
                        float* __restrict__ part, int M){
  __shared__ __align__(16) char smem[64*256];   // 64 rows x 128 bf16 (256B rows), swizzled
  __shared__ float rbuf[8];
  const int tid = threadIdx.x;
  const int m0 = blockIdx.x * 64;
  const int wave = tid >> 6, lane = tid & 63;
  const int lr = lane & 15, lc = lane >> 4;

  bf16x8 bf[4][4];
  #pragma unroll
  for (int nf = 0; nf < 4; ++nf){
    int n = wave*64 + nf*16 + lr;
    #pragma unroll
    for (int ks = 0; ks < 4; ++ks)
      bf[nf][ks] = *(const bf16x8*)(Bt + n*128 + ks*32 + lc*8);
  }
  #pragma unroll
  for (int p = 0; p < 4; ++p){
    int idx = p*256 + tid;
    int row = idx >> 4, ch = idx & 15;
    int r = m0 + row;
    uint4 v = make_uint4(0u,0u,0u,0u);
    if (r < M) v = *(const uint4*)(A + r*128 + ch*8);
    int o = (row*256 + ch*16) ^ ((row & 7) << 4);
    *(uint4*)(smem + o) = v;
  }
  __syncthreads();

  f32x4 acc[4][4] = {};
  #pragma unroll
  for (int ks = 0; ks < 4; ++ks){
    bf16x8 a[4];
    #pragma unroll
    for (int mf = 0; mf < 4; ++mf){
      int row = mf*16 + lr;
      int o = (row*256 + ks*64 + lc*16) ^ ((row & 7) << 4);
      a[mf] = *(const bf16x8*)(smem + o);
    }
    #pragma unroll
    for (int mf = 0; mf < 4; ++mf)
      #pragma unroll
      for (int nf = 0; nf < 4; ++nf)
        acc[mf][nf] = __builtin_amdgcn_mfma_f32_16x16x32_bf16(a[mf], bf[nf][ks], acc[mf][nf], 0, 0, 0);
  }

  float s1 = 0.f, s2 = 0.f;
  #pragma unroll
  for (int mf = 0; mf < 4; ++mf){
    #pragma unroll
    for (int j = 0; j < 4; ++j){
      int r = m0 + mf*16 + lc*4 + j;
      if (r < M){
        #pragma unroll
        for (int nf = 0; nf < 4; ++nf){
          int col = wave*64 + nf*16 + lr;
          float v = acc[mf][nf][j] + b1[col];
          H1[r*H_DIM + col] = f2bf(v);
          s1 += v; s2 += v*v;
        }
      }
    }
  }
  #pragma unroll
  for (int o = 32; o; o >>= 1){ s1 += __shfl_down(s1, o); s2 += __shfl_down(s2, o); }
  if (lane == 0){ rbuf[wave] = s1; rbuf[4 + wave] = s2; }
  __syncthreads();
  if (tid == 0)
    part[blockIdx.x*2]     = rbuf[0]+rbuf[1]+rbuf[2]+rbuf[3];
  if (tid == 1)
    part[blockIdx.x*2 + 1] = rbuf[4]+rbuf[5]+rbuf[6]+rbuf[7];
}

// ---- GEMM2: x_out = x_in + relu(LN(H1))(bf16) @ W2t^T + b2 ; LN coef block-local;
//      writes next-layer GN partials; last layer: fused final linear to out --------------
__global__ void k_gemm2(const unsigned short* __restrict__ H1,
                        const float* __restrict__ lnpart, int nparts,
                        const float* __restrict__ lnw, const float* __restrict__ lnb,
                        const unsigned short* __restrict__ Bt, const float* __restrict__ b2,
                        const float* __restrict__ Xin, float* __restrict__ Xout,
                        float* __restrict__ part, int NB,
                        const float* __restrict__ lw, const float* __restrict__ lb,
                        float* __restrict__ out, int M){
  __shared__ __align__(16) char smem[64*512];   // 64 rows x 256 bf16 (512B rows), swizzled
  __shared__ float red1[256], red2[256];
  __shared__ float colw[256], colb[256];
  __shared__ float rowdot[64];
  const int tid = threadIdx.x;
  const int m0 = blockIdx.x * 64;
  const int wave = tid >> 6, lane = tid & 63;
  const int lr = lane & 15, lc = lane >> 4;
  const bool last = (lw != nullptr);

  // ---- LN coefficients (block-local deterministic reduction of lnpart) ----
  {
    float s1 = 0.f, s2 = 0.f;
    for (int i = tid; i < nparts; i += 256){ s1 += lnpart[2*i]; s2 += lnpart[2*i+1]; }
    red1[tid] = s1; red2[tid] = s2; __syncthreads();
    for (int o = 128; o; o >>= 1){
      if (tid < o){ red1[tid] += red1[tid+o]; red2[tid] += red2[tid+o]; }
      __syncthreads();
    }
    double NH = (double)M * (double)H_DIM;
    double mean = (double)red1[0] / NH;
    double var = (double)red2[0] / NH - mean*mean;
    double sd = sqrt(var > 0.0 ? var : 0.0);
    float denom = (float)sd + 1e-5f;
    float wv = lnw[tid] / denom;
    colw[tid] = wv;
    colb[tid] = lnb[tid] - (float)mean * wv;
    if (tid < 64) rowdot[tid] = 0.f;
    __syncthreads();
  }

  bf16x8 bf[2][8];
  #pragma unroll
  for (int nf = 0; nf < 2; ++nf){
    int n = wave*32 + nf*16 + lr;
    #pragma unroll
    for (int ks = 0; ks < 8; ++ks)
      bf[nf][ks] = *(const bf16x8*)(Bt + n*256 + ks*32 + lc*8);
  }
  #pragma unroll
  for (int p = 0; p < 8; ++p){
    int idx = (p*256 + tid)*8;
    int row = idx >> 8, col = idx & 255;
    int r = m0 + row;
    uint4 v = make_uint4(0u,0u,0u,0u);
    if (r < M) v = *(const uint4*)(H1 + r*H_DIM + col);
    unsigned short hb[8] = {(unsigned short)(v.x&0xffff),(unsigned short)(v.x>>16),
                            (unsigned short)(v.y&0xffff),(unsigned short)(v.y>>16),
                            (unsigned short)(v.z&0xffff),(unsigned short)(v.z>>16),
                            (unsigned short)(v.w&0xffff),(unsigned short)(v.w>>16)};
    unsigned outp[4];
    #pragma unroll
    for (int q = 0; q < 4; ++q){
      float f0 = fmaxf(colw[col+2*q]  *bf2f(hb[2*q])   + colb[col+2*q],   0.f);
      float f1 = fmaxf(colw[col+2*q+1]*bf2f(hb[2*q+1]) + colb[col+2*q+1], 0.f);
      outp[q] = (unsigned)f2bf(f0) | ((unsigned)f2bf(f1) << 16);
    }
    int o = (row*512 + col*2) ^ ((row & 7) << 4);
    *(uint4*)(smem + o) = make_uint4(outp[0],outp[1],outp[2],outp[3]);
  }
  __syncthreads();

  f32x4 acc[4][2] = {};
  #pragma unroll
  for (int ks = 0; ks < 8; ++ks){
    bf16x8 a[4];
    #pragma unroll
    for (int mf = 0; mf < 4; ++mf){
      int row = mf*16 + lr;
      int o = (row*512 + ks*64 + lc*16) ^ ((row & 7) << 4);
      a[mf] = *(const bf16x8*)(smem + o);
    }
    #pragma unroll
    for (int mf = 0; mf < 4; ++mf)
      #pragma unroll
      for (int nf = 0; nf < 2; ++nf)
        acc[mf][nf] = __builtin_amdgcn_mfma_f32_16x16x32_bf16(a[mf], bf[nf][ks], acc[mf][nf], 0, 0, 0);
  }

  float sA[2] = {0.f, 0.f}, sB[2] = {0.f, 0.f};
  #pragma unroll
  for (int mf = 0; mf < 4; ++mf){
    #pragma unroll
    for (int j = 0; j < 4; ++j){
      int r = m0 + mf*16 + lc*4 + j;
      if (r < M){
        float p = 0.f;
        #pragma unroll
        for (int nf = 0; nf < 2; ++nf){
          int col = wave*32 + nf*16 + lr;
          float v = Xin[r*C_DIM + col] + acc[mf][nf][j] + b2[col];
          if (!last){
            Xout[r*C_DIM + col] = v;
            sA[nf] += v; sB[nf] += v*v;
          } else {
            p += v * lw[col];
          }
        }
        if (last){
          p += __shfl_xor(p, 1); p += __shfl_xor(p, 2);
          p += __shfl_xor(p, 4); p += __shfl_xor(p, 8);
          if (lr == 0) atomicAdd(&rowdot[r - m0], p);
        }
      }
    }
  }
  if (!last){
    #pragma unroll
    for (int nf = 0; nf < 2; ++nf){
      sA[nf] += __shfl_xor(sA[nf], 16); sA[nf] += __shfl_xor(sA[nf], 32);
      sB[nf] += __shfl_xor(sB[nf], 16); sB[nf] += __shfl_xor(sB[nf], 32);
    }
    if (lane < 16){
      #pragma unroll
      for (int nf = 0; nf < 2; ++nf){
        int col = wave*32 + nf*16 + lr;
        part[col*NB + blockIdx.x]       = sA[nf];
        part[(128+col)*NB + blockIdx.x] = sB[nf];
      }
    }
  } else {
    __syncthreads();
    if (tid < 64 && m0 + tid < M) out[m0 + tid] = rowdot[tid] + lb[0];
  }
}

extern "C" void kernel_launch(void* const* d_in, const int* in_sizes, int n_in,
                              void* d_out, int out_size, void* d_ws, size_t ws_size,
                              hipStream_t stream){
  const float* x    = (const float*)d_in[0];
  const int*   src  = (const int*)d_in[1];
  const int*   dst  = (const int*)d_in[2];
  const float* W1   = (const float*)d_in[3];
  const float* b1   = (const float*)d_in[4];
  const float* lnw  = (const float*)d_in[5];
  const float* lnb  = (const float*)d_in[6];
  const float* W2   = (const float*)d_in[7];
  const float* b2   = (const float*)d_in[8];
  const float* tpt  = (const float*)d_in[9];
  const float* gnw  = (const float*)d_in[10];
  const float* gnb  = (const float*)d_in[11];
  const float* gna  = (const float*)d_in[12];
  const float* linw = (const float*)d_in[13];
  const float* linb = (const float*)d_in[14];
  (void)n_in; (void)out_size; (void)ws_size;
  const int N = in_sizes[0] / C_DIM;
  const int E = in_sizes[1];
  float* out = (float*)d_out;

  const int gmw = (N + 63)/64;          // gemm blocks (64 rows each)
  const int S0  = (N + 127)/128;        // stat0 blocks
  const int NB  = gmw;                  // partial-stat stride

  char* wsp = (char*)d_ws; size_t off = 0;
  auto alloc = [&](size_t b)->char*{ char* p = wsp + off; off += (b + 255) & ~(size_t)255; return p; };
  int* cnt          = (int*)alloc((size_t)N*4);
  int* rp           = (int*)alloc((size_t)(N+1)*4);
  int* bsum         = (int*)alloc(1024);
  int* boff         = (int*)alloc(1024);
  float* gncoef     = (float*)alloc(1024);
  float* lnpart     = (float*)alloc((size_t)gmw*2*4);
  float* part       = (float*)alloc((size_t)NB*256*4);   // column-major per-block GN partials
  int* csrc         = (int*)alloc((size_t)E*4);
  unsigned short* W1t = (unsigned short*)alloc((size_t)L_NUM*C_DIM*H_DIM*2);
  unsigned short* W2t = (unsigned short*)alloc((size_t)L_NUM*C_DIM*H_DIM*2);
  unsigned* g       = (unsigned*)alloc((size_t)N*C_DIM*2);   // bf16 [N][128]
  unsigned short* U = (unsigned short*)alloc((size_t)N*C_DIM*2);
  unsigned short* h1 = (unsigned short*)alloc((size_t)N*H_DIM*2);
  float* xc         = (float*)alloc((size_t)N*C_DIM*4);

  const int SB = (N + 255)/256;
  hipMemsetAsync(cnt, 0, (size_t)N*4, stream);
  k_pre<<<512 + S0 + 1024, 256, 0, stream>>>(W1, W2, W1t, W2t, x, part, NB, dst, cnt, N, E, S0);
  k_scan_local<<<SB, 256, 0, stream>>>(cnt, rp, bsum, N);
  k_scan_bsums<<<1, 256, 0, stream>>>(bsum, boff, SB);
  k_scan_add<<<SB, 256, 0, stream>>>(rp, boff, cnt, N, E);
  k_scatter<<<1024, 256, 0, stream>>>(src, dst, rp, cnt, csrc, E);

  for (int l = 0; l < L_NUM; ++l){
    int nb = (l == 0) ? S0 : gmw;
    const float* Xin = (l == 0) ? x : xc;
    bool lastL = (l == L_NUM - 1);
    k_gn_coef<<<128, 256, 0, stream>>>(part, NB, nb, gnw + l*C_DIM, gnb + l*C_DIM, gna + l*C_DIM, tpt, l, gncoef, N);
    k_gpre<<<(N*32 + 255)/256, 256, 0, stream>>>(Xin, gncoef, g, N*32);
    k_agg<<<(N + 1)/2, 128, 0, stream>>>(g, rp, csrc, tpt, l, U, N);
    k_gemm1<<<gmw, 256, 0, stream>>>(U, W1t + (size_t)l*C_DIM*H_DIM, b1 + l*H_DIM, h1, lnpart, N);
    k_gemm2<<<gmw, 256, 0, stream>>>(h1, lnpart, gmw, lnw + l*H_DIM, lnb + l*H_DIM,
                                     W2t + (size_t)l*C_DIM*H_DIM, b2 + l*C_DIM,
                                     Xin, xc, part, NB,
                                     lastL ? linw : nullptr, linb, out, N);
  }
}

// Round 12
// 409.252 us; speedup vs baseline: 4.7805x; 1.0530x over previous
//
#include <hip/hip_runtime.h>

#define C_DIM 128
#define H_DIM 256
#define L_NUM 4

typedef __attribute__((ext_vector_type(8))) short bf16x8;
typedef __attribute__((ext_vector_type(4))) float f32x4;

__device__ __forceinline__ unsigned short f2bf(float f){
  unsigned u = __builtin_bit_cast(unsigned, f);
  u = u + 0x7FFFu + ((u >> 16) & 1u);   // round-to-nearest-even
  return (unsigned short)(u >> 16);
}
__device__ __forceinline__ float bf2f(unsigned short b){
  return __builtin_bit_cast(float, ((unsigned)b) << 16);
}
__device__ __forceinline__ float fexp2(float x){
#if __has_builtin(__builtin_amdgcn_exp2f)
  return __builtin_amdgcn_exp2f(x);      // single v_exp_f32
#else
  float r; asm("v_exp_f32 %0, %1" : "=v"(r) : "v"(x)); return r;
#endif
}

// ---- merged preamble: wconv (512 blocks) | stat0 (S0 blocks, latency-unrolled) | hist ----
__global__ void k_pre(const float* __restrict__ W1, const float* __restrict__ W2,
                      unsigned short* __restrict__ W1t, unsigned short* __restrict__ W2t,
                      const float* __restrict__ X, float* __restrict__ part, int NB,
                      const int* __restrict__ dst, int* __restrict__ cnt,
                      int N, int E, int S0){
  __shared__ float a1[256], a2[256];
  int b = blockIdx.x;
  if (b < 512){
    int i = b*256 + threadIdx.x;            // 512*256 == L*C*H exactly
    int l = i >> 15, r = i & 32767;
    { int k = r >> 8, n = r & 255;  W1t[l*32768 + n*128 + k] = f2bf(W1[i]); }
    { int k = r >> 7, n = r & 127;  W2t[l*32768 + n*256 + k] = f2bf(W2[i]); }
  } else if (b < 512 + S0){
    int chunk = b - 512;
    int t = threadIdx.x; int c = t & 127; int half = t >> 7;
    int r0 = chunk*128, rend = min(r0 + 128, N);
    // 4 independent accumulator pairs -> 4 loads in flight (latency hiding)
    float sa=0.f,sb=0.f,sc=0.f,sd=0.f, qa=0.f,qb=0.f,qc=0.f,qd=0.f;
    int r = r0 + half;
    for (; r + 6 < rend; r += 8){
      float v0 = X[(size_t)r*C_DIM + c];
      float v1 = X[(size_t)(r+2)*C_DIM + c];
      float v2 = X[(size_t)(r+4)*C_DIM + c];
      float v3 = X[(size_t)(r+6)*C_DIM + c];
      sa += v0; qa = fmaf(v0, v0, qa);
      sb += v1; qb = fmaf(v1, v1, qb);
      sc += v2; qc = fmaf(v2, v2, qc);
      sd += v3; qd = fmaf(v3, v3, qd);
    }
    for (; r < rend; r += 2){
      float v = X[(size_t)r*C_DIM + c];
      sa += v; qa = fmaf(v, v, qa);
    }
    float s = (sa + sb) + (sc + sd);
    float s2 = (qa + qb) + (qc + qd);
    a1[t] = s; a2[t] = s2; __syncthreads();
    if (t < 128){
      part[t*NB + chunk]       = a1[t] + a1[t+128];
      part[(128+t)*NB + chunk] = a2[t] + a2[t+128];
    }
  } else {
    int nb = gridDim.x - 512 - S0;
    int bb = b - 512 - S0;
    for (int e = bb*256 + threadIdx.x; e < E; e += nb*256)
      atomicAdd(cnt + dst[e], 1);
  }
}

__global__ void k_scan_local(const int* __restrict__ cnt, int* __restrict__ rp,
                             int* __restrict__ bsum, int N){
  __shared__ int tmp[256];
  int t = threadIdx.x; int i = blockIdx.x*256 + t;
  int v = (i < N) ? cnt[i] : 0;
  tmp[t] = v; __syncthreads();
  for (int off = 1; off < 256; off <<= 1){
    int x = (t >= off) ? tmp[t-off] : 0; __syncthreads();
    tmp[t] += x; __syncthreads();
  }
  if (i < N) rp[i] = tmp[t] - v;              // exclusive within block
  if (t == 255) bsum[blockIdx.x] = tmp[t];
}

__global__ void k_scan_bsums(const int* __restrict__ bsum, int* __restrict__ boff, int nb){
  __shared__ int tmp[256];
  int t = threadIdx.x;
  int v = (t < nb) ? bsum[t] : 0;
  tmp[t] = v; __syncthreads();
  for (int off = 1; off < 256; off <<= 1){
    int x = (t >= off) ? tmp[t-off] : 0; __syncthreads();
    tmp[t] += x; __syncthreads();
  }
  if (t < nb) boff[t] = tmp[t] - v;           // exclusive
}

// adds block offsets AND re-zeros cnt for the scatter pass
__global__ void k_scan_add(int* __restrict__ rp, const int* __restrict__ boff,
                           int* __restrict__ cnt, int N, int E){
  int i = blockIdx.x*256 + threadIdx.x;
  if (i < N){ rp[i] += boff[blockIdx.x]; cnt[i] = 0; }
  if (i == 0) rp[N] = E;
}

__global__ void k_scatter(const int* __restrict__ src, const int* __restrict__ dst,
                          const int* __restrict__ rp, int* __restrict__ cnt,
                          int* __restrict__ csrc, int E){
  for (int e = blockIdx.x*blockDim.x + threadIdx.x; e < E; e += gridDim.x*blockDim.x){
    int d = dst[e];
    int pos = rp[d] + atomicAdd(cnt + d, 1);
    csrc[pos] = src[e];
  }
}

// ---- graph norm: reduce partials + coef (pre-scaled by kk = t*log2(e)), 1 block/channel ----
__global__ void k_gn_coef(const float* __restrict__ part, int NB, int nb,
                          const float* __restrict__ gw, const float* __restrict__ gb,
                          const float* __restrict__ ga, const float* __restrict__ tptr, int l,
                          float* __restrict__ coef, int N){
  int c = blockIdx.x;       // 0..127
  int t = threadIdx.x;      // 256
  float s = 0.f, s2 = 0.f;
  for (int i = t; i < nb; i += 256){
    s  += part[c*NB + i];
    s2 += part[(128+c)*NB + i];
  }
  __shared__ float sh1[256], sh2[256];
  sh1[t] = s; sh2[t] = s2; __syncthreads();
  for (int off = 128; off; off >>= 1){
    if (t < off){ sh1[t] += sh1[t+off]; sh2[t] += sh2[t+off]; }
    __syncthreads();
  }
  if (t == 0){
    float kk = tptr[l] * 1.4426950408889634f;
    float inv = 1.f/(float)N;
    float mean = sh1[0]*inv;
    float am = ga[c]*mean;
    float var = sh2[0]*inv - 2.f*am*mean + am*am;   // E[(x - a*mean)^2]
    float scale = gw[c] * rsqrtf(var + 1e-5f);
    coef[c] = scale * kk;
    coef[128+c] = (gb[c] - scale*am) * kk;
  }
}

// ---------------- g = kk * relu(affine(x)) in bf16 (affine already kk-scaled) ----------------
__global__ void k_gpre(const float* __restrict__ X, const float* __restrict__ coef,
                       unsigned* __restrict__ G2, int total4){
  int i = blockIdx.x*blockDim.x + threadIdx.x;
  if (i >= total4) return;
  int c4 = i & 31;
  float4 x = ((const float4*)X)[i];
  float4 A = ((const float4*)coef)[c4];
  float4 B = ((const float4*)coef)[32 + c4];
  float o0 = fmaxf(A.x*x.x + B.x, 0.f);
  float o1 = fmaxf(A.y*x.y + B.y, 0.f);
  float o2 = fmaxf(A.z*x.z + B.z, 0.f);
  float o3 = fmaxf(A.w*x.w + B.w, 0.f);
  uint2 pk = make_uint2((unsigned)f2bf(o0) | ((unsigned)f2bf(o1) << 16),
                        (unsigned)f2bf(o2) | ((unsigned)f2bf(o3) << 16));
  ((uint2*)G2)[i] = pk;
}

// ---- softmax aggregation: wave-uniform SCALAR index loads (s_load via readfirstlane),
//      saddr-form gathers, 8-deep pipeline, A/B accumulator alternation ----
__global__ void k_agg(const unsigned* __restrict__ G, const int* __restrict__ rp,
                      const int* __restrict__ csrc, const float* __restrict__ tptr, int l,
                      unsigned short* __restrict__ U, int N){
  int wave = threadIdx.x >> 6, lane = threadIdx.x & 63;
  int n = blockIdx.x*2 + wave;
  if (n >= N) return;
  float invkk = 1.f / (tptr[l] * 1.4426950408889634f);
  int jb = __builtin_amdgcn_readfirstlane(rp[n]);
  int je = __builtin_amdgcn_readfirstlane(rp[n+1]);
  float dA0=0.f,dA1=0.f,sA0=0.f,sA1=0.f;
  float dB0=0.f,dB1=0.f,sB0=0.f,sB1=0.f;
  unsigned uo = G[(size_t)n*64 + lane];   // self row, prefetched

  #define EDGEA(uu) { \
    float p0 = __builtin_bit_cast(float, (uu) << 16); \
    float p1 = __builtin_bit_cast(float, (uu) & 0xffff0000u); \
    float e0 = fexp2(p0); float e1 = fexp2(p1); \
    dA0 += e0; dA1 += e1; \
    sA0 = fmaf(p0, e0, sA0); sA1 = fmaf(p1, e1, sA1); }
  #define EDGEB(uu) { \
    float p0 = __builtin_bit_cast(float, (uu) << 16); \
    float p1 = __builtin_bit_cast(float, (uu) & 0xffff0000u); \
    float e0 = fexp2(p0); float e1 = fexp2(p1); \
    dB0 += e0; dB1 += e1; \
    sB0 = fmaf(p0, e0, sB0); sB1 = fmaf(p1, e1, sB1); }

  int j = jb;
  for (; j + 7 < je; j += 8){
    int i0 = csrc[j+0], i1 = csrc[j+1], i2 = csrc[j+2], i3 = csrc[j+3];
    int i4 = csrc[j+4], i5 = csrc[j+5], i6 = csrc[j+6], i7 = csrc[j+7];
    unsigned v0 = G[(size_t)i0*64 + lane];
    unsigned v1 = G[(size_t)i1*64 + lane];
    unsigned v2 = G[(size_t)i2*64 + lane];
    unsigned v3 = G[(size_t)i3*64 + lane];
    unsigned v4 = G[(size_t)i4*64 + lane];
    unsigned v5 = G[(size_t)i5*64 + lane];
    unsigned v6 = G[(size_t)i6*64 + lane];
    unsigned v7 = G[(size_t)i7*64 + lane];
    EDGEA(v0); EDGEB(v1); EDGEA(v2); EDGEB(v3);
    EDGEA(v4); EDGEB(v5); EDGEA(v6); EDGEB(v7);
  }
  for (; j + 3 < je; j += 4){
    int i0 = csrc[j+0], i1 = csrc[j+1], i2 = csrc[j+2], i3 = csrc[j+3];
    unsigned v0 = G[(size_t)i0*64 + lane];
    unsigned v1 = G[(size_t)i1*64 + lane];
    unsigned v2 = G[(size_t)i2*64 + lane];
    unsigned v3 = G[(size_t)i3*64 + lane];
    EDGEA(v0); EDGEB(v1); EDGEA(v2); EDGEB(v3);
  }
  for (; j < je; ++j){
    int i0 = csrc[j];
    unsigned v0 = G[(size_t)i0*64 + lane];
    EDGEA(v0);
  }
  #undef EDGEA
  #undef EDGEB

  float d0 = dA0 + dB0, d1 = dA1 + dB1;
  float s0 = sA0 + sB0, s1 = sA1 + sB1;
  float o0 = __builtin_bit_cast(float, uo << 16);
  float o1 = __builtin_bit_cast(float, uo & 0xffff0000u);
  float u0 = invkk * (s0/(d0 + 1e-16f) + o0) + 1e-7f;
  float u1 = invkk * (s1/(d1 + 1e-16f) + o1) + 1e-7f;
  unsigned pk = (unsigned)f2bf(u0) | ((unsigned)f2bf(u1) << 16);
  *(unsigned*)(U + n*C_DIM + lane*2) = pk;
}

// ---------------- GEMM1: h1(bf16) = U(bf16)[M,128] @ W1t^T + b1 ; per-block LN partials ----
__global__ void k_gemm1(const unsigned short* __restrict__ A, const unsigned short* __restrict__ Bt,
                        const float* __restrict__ b1, unsigned short* __restrict__ H1,
                        float* __restrict__ part, int M){
  __shared__ __align__(16) char smem[64*256];   // 64 rows x 128 bf16 (256B rows), swizzled
  __shared__ float rbuf[8];
  const int tid = threadIdx.x;
  const int m0 = blockIdx.x * 64;
  const int wave = tid >> 6, lane = tid & 63;
  const int lr = lane & 15, lc = lane >> 4;

  bf16x8 bf[4][4];
  #pragma unroll
  for (int nf = 0; nf < 4; ++nf){
    int n = wave*64 + nf*16 + lr;
    #pragma unroll
    for (int ks = 0; ks < 4; ++ks)
      bf[nf][ks] = *(const bf16x8*)(Bt + n*128 + ks*32 + lc*8);
  }
  #pragma unroll
  for (int p = 0; p < 4; ++p){
    int idx = p*256 + tid;
    int row = idx >> 4, ch = idx & 15;
    int r = m0 + row;
    uint4 v = make_uint4(0u,0u,0u,0u);
    if (r < M) v = *(const uint4*)(A + r*128 + ch*8);
    int o = (row*256 + ch*16) ^ ((row & 7) << 4);
    *(uint4*)(smem + o) = v;
  }
  __syncthreads();

  f32x4 acc[4][4] = {};
  #pragma unroll
  for (int ks = 0; ks < 4; ++ks){
    bf16x8 a[4];
    #pragma unroll
    for (int mf = 0; mf < 4; ++mf){
      int row = mf*16 + lr;
      int o = (row*256 + ks*64 + lc*16) ^ ((row & 7) << 4);
      a[mf] = *(const bf16x8*)(smem + o);
    }
    #pragma unroll
    for (int mf = 0; mf < 4; ++mf)
      #pragma unroll
      for (int nf = 0; nf < 4; ++nf)
        acc[mf][nf] = __builtin_amdgcn_mfma_f32_16x16x32_bf16(a[mf], bf[nf][ks], acc[mf][nf], 0, 0, 0);
  }

  float s1 = 0.f, s2 = 0.f;
  #pragma unroll
  for (int mf = 0; mf < 4; ++mf){
    #pragma unroll
    for (int j = 0; j < 4; ++j){
      int r = m0 + mf*16 + lc*4 + j;
      if (r < M){
        #pragma unroll
        for (int nf = 0; nf < 4; ++nf){
          int col = wave*64 + nf*16 + lr;
          float v = acc[mf][nf][j] + b1[col];
          H1[r*H_DIM + col] = f2bf(v);
          s1 += v; s2 += v*v;
        }
      }
    }
  }
  #pragma unroll
  for (int o = 32; o; o >>= 1){ s1 += __shfl_down(s1, o); s2 += __shfl_down(s2, o); }
  if (lane == 0){ rbuf[wave] = s1; rbuf[4 + wave] = s2; }
  __syncthreads();
  if (tid == 0)
    part[blockIdx.x*2]     = rbuf[0]+rbuf[1]+rbuf[2]+rbuf[3];
  if (tid == 1)
    part[blockIdx.x*2 + 1] = rbuf[4]+rbuf[5]+rbuf[6]+rbuf[7];
}

// ---- GEMM2: x_out = x_in + relu(LN(H1))(bf16) @ W2t^T + b2 ; LN coef block-local;
//      writes next-layer GN partials; last layer: fused final linear to out --------------
__global__ void k_gemm2(const unsigned short* __restrict__ H1,
                        const float* __restrict__ lnpart, int nparts,
                        const float* __restrict__ lnw, const float* __restrict__ lnb,
                        const unsigned short* __restrict__ Bt, const float* __restrict__ b2,
                        const float* __restrict__ Xin, float* __restrict__ Xout,
                        float* __restrict__ part, int NB,
                        const float* __restrict__ lw, const float* __restrict__ lb,
                        float* __restrict__ out, int M){
  __shared__ __align__(16) char smem[64*512];   // 64 rows x 256 bf16 (512B rows), swizzled
  __shared__ float red1[256], red2[256];
  __shared__ float colw[256], colb[256];
  __shared__ float rowdot[64];
  const int tid = threadIdx.x;
  const int m0 = blockIdx.x * 64;
  const int wave = tid >> 6, lane = tid & 63;
  const int lr = lane & 15, lc = lane >> 4;
  const bool last = (lw != nullptr);

  // ---- LN coefficients (block-local deterministic reduction of lnpart) ----
  {
    float s1 = 0.f, s2 = 0.f;
    for (int i = tid; i < nparts; i += 256){ s1 += lnpart[2*i]; s2 += lnpart[2*i+1]; }
    red1[tid] = s1; red2[tid] = s2; __syncthreads();
    for (int o = 128; o; o >>= 1){
      if (tid < o){ red1[tid] += red1[tid+o]; red2[tid] += red2[tid+o]; }
      __syncthreads();
    }
    double NH = (double)M * (double)H_DIM;
    double mean = (double)red1[0] / NH;
    double var = (double)red2[0] / NH - mean*mean;
    double sd = sqrt(var > 0.0 ? var : 0.0);
    float denom = (float)sd + 1e-5f;
    float wv = lnw[tid] / denom;
    colw[tid] = wv;
    colb[tid] = lnb[tid] - (float)mean * wv;
    if (tid < 64) rowdot[tid] = 0.f;
    __syncthreads();
  }

  bf16x8 bf[2][8];
  #pragma unroll
  for (int nf = 0; nf < 2; ++nf){
    int n = wave*32 + nf*16 + lr;
    #pragma unroll
    for (int ks = 0; ks < 8; ++ks)
      bf[nf][ks] = *(const bf16x8*)(Bt + n*256 + ks*32 + lc*8);
  }
  #pragma unroll
  for (int p = 0; p < 8; ++p){
    int idx = (p*256 + tid)*8;
    int row = idx >> 8, col = idx & 255;
    int r = m0 + row;
    uint4 v = make_uint4(0u,0u,0u,0u);
    if (r < M) v = *(const uint4*)(H1 + r*H_DIM + col);
    unsigned short hb[8] = {(unsigned short)(v.x&0xffff),(unsigned short)(v.x>>16),
                            (unsigned short)(v.y&0xffff),(unsigned short)(v.y>>16),
                            (unsigned short)(v.z&0xffff),(unsigned short)(v.z>>16),
                            (unsigned short)(v.w&0xffff),(unsigned short)(v.w>>16)};
    unsigned outp[4];
    #pragma unroll
    for (int q = 0; q < 4; ++q){
      float f0 = fmaxf(colw[col+2*q]  *bf2f(hb[2*q])   + colb[col+2*q],   0.f);
      float f1 = fmaxf(colw[col+2*q+1]*bf2f(hb[2*q+1]) + colb[col+2*q+1], 0.f);
      outp[q] = (unsigned)f2bf(f0) | ((unsigned)f2bf(f1) << 16);
    }
    int o = (row*512 + col*2) ^ ((row & 7) << 4);
    *(uint4*)(smem + o) = make_uint4(outp[0],outp[1],outp[2],outp[3]);
  }
  __syncthreads();

  f32x4 acc[4][2] = {};
  #pragma unroll
  for (int ks = 0; ks < 8; ++ks){
    bf16x8 a[4];
    #pragma unroll
    for (int mf = 0; mf < 4; ++mf){
      int row = mf*16 + lr;
      int o = (row*512 + ks*64 + lc*16) ^ ((row & 7) << 4);
      a[mf] = *(const bf16x8*)(smem + o);
    }
    #pragma unroll
    for (int mf = 0; mf < 4; ++mf)
      #pragma unroll
      for (int nf = 0; nf < 2; ++nf)
        acc[mf][nf] = __builtin_amdgcn_mfma_f32_16x16x32_bf16(a[mf], bf[nf][ks], acc[mf][nf], 0, 0, 0);
  }

  float sA[2] = {0.f, 0.f}, sB[2] = {0.f, 0.f};
  #pragma unroll
  for (int mf = 0; mf < 4; ++mf){
    #pragma unroll
    for (int j = 0; j < 4; ++j){
      int r = m0 + mf*16 + lc*4 + j;
      if (r < M){
        float p = 0.f;
        #pragma unroll
        for (int nf = 0; nf < 2; ++nf){
          int col = wave*32 + nf*16 + lr;
          float v = Xin[r*C_DIM + col] + acc[mf][nf][j] + b2[col];
          if (!last){
            Xout[r*C_DIM + col] = v;
            sA[nf] += v; sB[nf] += v*v;
          } else {
            p += v * lw[col];
          }
        }
        if (last){
          p += __shfl_xor(p, 1); p += __shfl_xor(p, 2);
          p += __shfl_xor(p, 4); p += __shfl_xor(p, 8);
          if (lr == 0) atomicAdd(&rowdot[r - m0], p);
        }
      }
    }
  }
  if (!last){
    #pragma unroll
    for (int nf = 0; nf < 2; ++nf){
      sA[nf] += __shfl_xor(sA[nf], 16); sA[nf] += __shfl_xor(sA[nf], 32);
      sB[nf] += __shfl_xor(sB[nf], 16); sB[nf] += __shfl_xor(sB[nf], 32);
    }
    if (lane < 16){
      #pragma unroll
      for (int nf = 0; nf < 2; ++nf){
        int col = wave*32 + nf*16 + lr;
        part[col*NB + blockIdx.x]       = sA[nf];
        part[(128+col)*NB + blockIdx.x] = sB[nf];
      }
    }
  } else {
    __syncthreads();
    if (tid < 64 && m0 + tid < M) out[m0 + tid] = rowdot[tid] + lb[0];
  }
}

extern "C" void kernel_launch(void* const* d_in, const int* in_sizes, int n_in,
                              void* d_out, int out_size, void* d_ws, size_t ws_size,
                              hipStream_t stream){
  const float* x    = (const float*)d_in[0];
  const int*   src  = (const int*)d_in[1];
  const int*   dst  = (const int*)d_in[2];
  const float* W1   = (const float*)d_in[3];
  const float* b1   = (const float*)d_in[4];
  const float* lnw  = (const float*)d_in[5];
  const float* lnb  = (const float*)d_in[6];
  const float* W2   = (const float*)d_in[7];
  const float* b2   = (const float*)d_in[8];
  const float* tpt  = (const float*)d_in[9];
  const float* gnw  = (const float*)d_in[10];
  const float* gnb  = (const float*)d_in[11];
  const float* gna  = (const float*)d_in[12];
  const float* linw = (const float*)d_in[13];
  const float* linb = (const float*)d_in[14];
  (void)n_in; (void)out_size; (void)ws_size;
  const int N = in_sizes[0] / C_DIM;
  const int E = in_sizes[1];
  float* out = (float*)d_out;

  const int gmw = (N + 63)/64;          // gemm blocks (64 rows each)
  const int S0  = (N + 127)/128;        // stat0 blocks
  const int NB  = gmw;                  // partial-stat stride

  char* wsp = (char*)d_ws; size_t off = 0;
  auto alloc = [&](size_t b)->char*{ char* p = wsp + off; off += (b + 255) & ~(size_t)255; return p; };
  int* cnt          = (int*)alloc((size_t)N*4);
  int* rp           = (int*)alloc((size_t)(N+1)*4);
  int* bsum         = (int*)alloc(1024);
  int* boff         = (int*)alloc(1024);
  float* gncoef     = (float*)alloc(1024);
  float* lnpart     = (float*)alloc((size_t)gmw*2*4);
  float* part       = (float*)alloc((size_t)NB*256*4);   // column-major per-block GN partials
  int* csrc         = (int*)alloc((size_t)E*4);
  unsigned short* W1t = (unsigned short*)alloc((size_t)L_NUM*C_DIM*H_DIM*2);
  unsigned short* W2t = (unsigned short*)alloc((size_t)L_NUM*C_DIM*H_DIM*2);
  unsigned* g       = (unsigned*)alloc((size_t)N*C_DIM*2);   // bf16 [N][128]
  unsigned short* U = (unsigned short*)alloc((size_t)N*C_DIM*2);
  unsigned short* h1 = (unsigned short*)alloc((size_t)N*H_DIM*2);
  float* xc         = (float*)alloc((size_t)N*C_DIM*4);

  const int SB = (N + 255)/256;
  hipMemsetAsync(cnt, 0, (size_t)N*4, stream);
  k_pre<<<512 + S0 + 1024, 256, 0, stream>>>(W1, W2, W1t, W2t, x, part, NB, dst, cnt, N, E, S0);
  k_scan_local<<<SB, 256, 0, stream>>>(cnt, rp, bsum, N);
  k_scan_bsums<<<1, 256, 0, stream>>>(bsum, boff, SB);
  k_scan_add<<<SB, 256, 0, stream>>>(rp, boff, cnt, N, E);
  k_scatter<<<1024, 256, 0, stream>>>(src, dst, rp, cnt, csrc, E);

  for (int l = 0; l < L_NUM; ++l){
    int nb = (l == 0) ? S0 : gmw;
    const float* Xin = (l == 0) ? x : xc;
    bool lastL = (l == L_NUM - 1);
    k_gn_coef<<<128, 256, 0, stream>>>(part, NB, nb, gnw + l*C_DIM, gnb + l*C_DIM, gna + l*C_DIM, tpt, l, gncoef, N);
    k_gpre<<<(N*32 + 255)/256, 256, 0, stream>>>(Xin, gncoef, g, N*32);
    k_agg<<<(N + 1)/2, 128, 0, stream>>>(g, rp, csrc, tpt, l, U, N);
    k_gemm1<<<gmw, 256, 0, stream>>>(U, W1t + (size_t)l*C_DIM*H_DIM, b1 + l*H_DIM, h1, lnpart, N);
    k_gemm2<<<gmw, 256, 0, stream>>>(h1, lnpart, gmw, lnw + l*H_DIM, lnb + l*H_DIM,
                                     W2t + (size_t)l*C_DIM*H_DIM, b2 + l*C_DIM,
                                     Xin, xc, part, NB,
                                     lastL ? linw : nullptr, linb, out, N);
  }
}